// Round 5
// baseline (286.089 us; speedup 1.0000x reference)
//
#include <hip/hip_runtime.h>
#include <hip/hip_bf16.h>

typedef __bf16 bf16_t;
typedef __bf16 bf16x8 __attribute__((ext_vector_type(8)));
typedef float f32x4 __attribute__((ext_vector_type(4)));

#define MFMA16(a, b, c) __builtin_amdgcn_mfma_f32_16x16x32_bf16(a, b, c, 0, 0, 0)

__device__ __forceinline__ void async_copy16(const void* g, void* l) {
  __builtin_amdgcn_global_load_lds(
      (const __attribute__((address_space(1))) void*)g,
      (__attribute__((address_space(3))) void*)l, 16, 0, 0);
}

// ---------------- cast f32 -> bf16 (8 elems/thread) ----------------
__global__ void cast_f32_bf16(const float* __restrict__ in, bf16_t* __restrict__ out, int n8) {
  int stride = gridDim.x * blockDim.x;
  for (int i = blockIdx.x * blockDim.x + threadIdx.x; i < n8; i += stride) {
    const float* p = in + (size_t)i * 8;
    f32x4 a = *(const f32x4*)p;
    f32x4 b = *(const f32x4*)(p + 4);
    bf16x8 o;
    o[0] = (bf16_t)a[0]; o[1] = (bf16_t)a[1]; o[2] = (bf16_t)a[2]; o[3] = (bf16_t)a[3];
    o[4] = (bf16_t)b[0]; o[5] = (bf16_t)b[1]; o[6] = (bf16_t)b[2]; o[7] = (bf16_t)b[3];
    *(bf16x8*)(out + (size_t)i * 8) = o;
  }
}

// ---------------- GEMM 256x128 tile, BK=64, 512 thr (8 waves 4Mx2N) ----------------
// counted-vmcnt double-buffer: stage tile t+1, vmcnt(6) waits tile t, never drains.
// C[m][n] = sum_k A[m][k] * Bw[n][k] (both K-major bf16)
// MODE 0: write f32 C row-major [M][N]
// MODE 1: fused epilogue via LDS roundtrip (RoPE for q/k, transpose for V)
template <int MODE>
__global__ __launch_bounds__(512, 2) void gemm256(
    const bf16_t* __restrict__ A, const bf16_t* __restrict__ Bw, float* __restrict__ C,
    bf16_t* __restrict__ qo, bf16_t* __restrict__ ko, bf16_t* __restrict__ vto,
    int M, int N, int K, int nby) {
  // LDS: A[buf] @ {0,32768} (256x64 bf16), B[buf] @ {65536,81920} (128x64 bf16)
  __shared__ __align__(16) char lds[98304];
  int tid = threadIdx.x;
  int w = tid >> 6, lane = tid & 63;
  int wm = w >> 1, wn = w & 1;
  int mr = lane & 15, kg = lane >> 4;

  // bijective XCD chunking + col-major decompose (B-panel L2 locality)
  int nwg = gridDim.x;
  int orig = blockIdx.x;
  int wgid = (orig & 7) * (nwg >> 3) + (orig >> 3);
  int by = wgid % nby, bx = wgid / nby;
  int row0 = by * 256, col0 = bx * 128;

  // staging source offsets: inverse-swizzled global (rule #21), linear LDS dest
  size_t aoff[4], boff[2];
#pragma unroll
  for (int it = 0; it < 4; ++it) {
    int c = tid + it * 512;
    int r = c >> 3;
    int chs = (c & 7) ^ (r & 7);
    aoff[it] = (size_t)(row0 + r) * K + chs * 8;
  }
#pragma unroll
  for (int it = 0; it < 2; ++it) {
    int c = tid + it * 512;
    int r = c >> 3;
    int chs = (c & 7) ^ (r & 7);
    boff[it] = (size_t)(col0 + r) * K + chs * 8;
  }

  auto stage = [&](int buf, int kt) {
    char* Ad = &lds[buf * 32768];
    char* Bd = &lds[65536 + buf * 16384];
#pragma unroll
    for (int it = 0; it < 4; ++it)
      async_copy16(A + aoff[it] + kt * 64, Ad + (tid + it * 512) * 16);
#pragma unroll
    for (int it = 0; it < 2; ++it)
      async_copy16(Bw + boff[it] + kt * 64, Bd + (tid + it * 512) * 16);
  };

  f32x4 zero = {0.f, 0.f, 0.f, 0.f};
  f32x4 acc[4][4];
#pragma unroll
  for (int mi = 0; mi < 4; ++mi)
#pragma unroll
    for (int ni = 0; ni < 4; ++ni) acc[mi][ni] = zero;

  int nt = K >> 6;
  stage(0, 0);
#pragma unroll 1
  for (int t = 0; t < nt; ++t) {
    int cur = t & 1;
    stage(cur ^ 1, (t + 1 < nt) ? (t + 1) : t);  // last iter: harmless dummy reload
    asm volatile("s_waitcnt vmcnt(6)" ::: "memory");  // tile t landed; t+1 in flight
    __builtin_amdgcn_sched_barrier(0);
    __builtin_amdgcn_s_barrier();
    __builtin_amdgcn_sched_barrier(0);
    const char* Ab = &lds[cur * 32768];
    const char* Bb = &lds[65536 + cur * 16384];
    bf16x8 af[4][2];
#pragma unroll
    for (int mi = 0; mi < 4; ++mi) {
      int row = wm * 64 + mi * 16 + mr;
      const char* rb = Ab + row * 128;
      int sz = (row & 7) << 4;
      af[mi][0] = *(const bf16x8*)(rb + ((kg * 16) ^ sz));
      af[mi][1] = *(const bf16x8*)(rb + ((64 + kg * 16) ^ sz));
    }
#pragma unroll
    for (int ni = 0; ni < 4; ++ni) {
      int row = wn * 64 + ni * 16 + mr;
      const char* rb = Bb + row * 128;
      int sz = (row & 7) << 4;
      bf16x8 b0 = *(const bf16x8*)(rb + ((kg * 16) ^ sz));
      bf16x8 b1 = *(const bf16x8*)(rb + ((64 + kg * 16) ^ sz));
      __builtin_amdgcn_s_setprio(1);
#pragma unroll
      for (int mi = 0; mi < 4; ++mi) {
        acc[mi][ni] = MFMA16(af[mi][0], b0, acc[mi][ni]);
        acc[mi][ni] = MFMA16(af[mi][1], b1, acc[mi][ni]);
      }
      __builtin_amdgcn_s_setprio(0);
    }
    __builtin_amdgcn_sched_barrier(0);
    __builtin_amdgcn_s_barrier();  // close buf[cur] reads before next overwrite
    __builtin_amdgcn_sched_barrier(0);
  }
  asm volatile("s_waitcnt vmcnt(0)" ::: "memory");
  __syncthreads();

  if (MODE == 0) {
#pragma unroll
    for (int mi = 0; mi < 4; ++mi)
#pragma unroll
      for (int ni = 0; ni < 4; ++ni)
#pragma unroll
        for (int jj = 0; jj < 4; ++jj) {
          int row = row0 + wm * 64 + mi * 16 + kg * 4 + jj;
          int col = col0 + wn * 64 + ni * 16 + mr;
          C[(size_t)row * N + col] = acc[mi][ni][jj];
        }
  } else {
    char* tb = &lds[0];
    int s = col0 >> 11, h = (col0 >> 7) & 15;
    int b = row0 >> 11, t0 = row0 & 2047;
    if (s < 2) {
      // ---- q/k: [t(256)][d(128)] bf16, 256B rows, swizzled ----
#pragma unroll
      for (int mi = 0; mi < 4; ++mi)
#pragma unroll
        for (int ni = 0; ni < 4; ++ni)
#pragma unroll
          for (int jj = 0; jj < 4; ++jj) {
            int rloc = wm * 64 + mi * 16 + kg * 4 + jj;
            int cb = (wn * 64 + ni * 16 + mr) * 2;
            *(bf16_t*)(tb + rloc * 256 + (cb ^ ((rloc & 7) << 4))) = (bf16_t)acc[mi][ni][jj];
          }
      __syncthreads();
      // ---- read half-row, apply RoPE, store contiguous ----
      int r = tid >> 1, hh = tid & 1;
      const char* rowb = tb + r * 256;
      int sz = (r & 7) << 4;
      int t = t0 + r;
      bf16_t* dst = (s == 0 ? qo : ko) + ((size_t)((b * 16 + h) * 2048 + t)) * 128 + hh * 64;
      float tf = (float)t;
      const float cinv = -0.20762050593046014f;  // -log2(10000)/64
#pragma unroll
      for (int m = 0; m < 8; ++m) {
        bf16x8 va = *(const bf16x8*)(rowb + ((hh * 128 + m * 16) ^ sz));
        bf16x8 vb = *(const bf16x8*)(rowb + (((hh ^ 1) * 128 + m * 16) ^ sz));
        bf16x8 o;
#pragma unroll
        for (int e = 0; e < 8; ++e) {
          float ang = tf * exp2f((float)(m * 8 + e) * cinv);
          float sv = __sinf(ang), cv = __cosf(ang);
          float x1 = (float)va[e], x2 = (float)vb[e];
          o[e] = (bf16_t)((hh == 0) ? (x1 * cv - x2 * sv) : (x1 * cv + x2 * sv));
        }
        *(bf16x8*)(dst + m * 8) = o;
      }
    } else {
      // ---- v: transposed [d(128)][t(256)] bf16, 512B rows, swizzled ----
#pragma unroll
      for (int mi = 0; mi < 4; ++mi)
#pragma unroll
        for (int ni = 0; ni < 4; ++ni)
#pragma unroll
          for (int jj = 0; jj < 4; ++jj) {
            int rloc = wm * 64 + mi * 16 + kg * 4 + jj;   // t
            int cloc = wn * 64 + ni * 16 + mr;            // d
            *(bf16_t*)(tb + cloc * 512 + ((rloc * 2) ^ ((cloc & 7) << 4))) =
                (bf16_t)acc[mi][ni][jj];
          }
      __syncthreads();
      int d = tid >> 2, qt = tid & 3;
      const char* rowb = tb + d * 512;
      int sz = (d & 7) << 4;
      bf16_t* dst = vto + ((size_t)((b * 16 + h) * 128 + d)) * 2048 + t0 + qt * 64;
#pragma unroll
      for (int m2 = 0; m2 < 8; ++m2)
        *(bf16x8*)(dst + m2 * 8) = *(const bf16x8*)(rowb + ((qt * 128 + m2 * 16) ^ sz));
    }
  }
}

// ---------------- causal flash attention (v2, unchanged) ----------------
__global__ __launch_bounds__(256) void attn_kernel(
    const bf16_t* __restrict__ qg, const bf16_t* __restrict__ kgl,
    const bf16_t* __restrict__ vtg, bf16_t* __restrict__ og) {
  __shared__ __align__(16) bf16_t Ks[2][64 * 128];
  __shared__ __align__(16) bf16_t Vs[2][128 * 64];
  __shared__ __align__(16) bf16_t plds[4][1024];
  const int T = 2048;
  int tid = threadIdx.x;
  int w = tid >> 6, lane = tid & 63;
  int mr = lane & 15, kg = lane >> 4;
  int swz = (mr & 7) << 4;

  int L = blockIdx.y * 16 + blockIdx.x;
  int role = (L & 7) * 64 + (L >> 3);
  int bx = role & 15, bh = role >> 4;

  const bf16_t* Q = qg + (size_t)bh * T * 128;
  const bf16_t* K = kgl + (size_t)bh * T * 128;
  const bf16_t* Vt = vtg + (size_t)bh * 128 * T;

  int sb = tid * 16;
  int krl = sb >> 8;
  int kc = (sb & 255) ^ ((krl & 7) << 4);
  size_t ksrc = (size_t)krl * 128 + (kc >> 1);
  int vdl = sb >> 7;
  int vc = (sb & 127) ^ ((vdl & 7) << 4);
  size_t vsrc = (size_t)vdl * 2048 + (vc >> 1);

  auto stage = [&](int buf, int kb) {
#pragma unroll
    for (int it = 0; it < 4; ++it)
      async_copy16(K + (size_t)(kb + it * 16) * 128 + ksrc, &Ks[buf][it * 2048 + tid * 8]);
#pragma unroll
    for (int it = 0; it < 4; ++it)
      async_copy16(Vt + (size_t)it * 65536 + kb + vsrc, &Vs[buf][it * 2048 + tid * 8]);
  };

  const float cscale = 0.12751744f;  // (1/sqrt(128)) * log2(e)
  f32x4 zero = {0.f, 0.f, 0.f, 0.f};
  bf16_t* P = &plds[w][0];
  int b = bh >> 4, h = bh & 15;

#pragma unroll 1
  for (int ph = 0; ph < 2; ++ph) {
    int qb = ph ? bx : (31 - bx);
    int qr0 = qb * 64 + w * 16;
    bf16x8 qf[4];
#pragma unroll
    for (int db = 0; db < 4; ++db)
      qf[db] = *(const bf16x8*)(Q + (size_t)(qr0 + mr) * 128 + db * 32 + kg * 8);

    f32x4 acc[8];
#pragma unroll
    for (int d2 = 0; d2 < 8; ++d2) acc[d2] = zero;
    float mrun[4] = {-1e30f, -1e30f, -1e30f, -1e30f};
    float lrun[4] = {0.f, 0.f, 0.f, 0.f};

    int nj = qb + 1;
    __syncthreads();
    stage(0, 0);
    int cur = 0;
#pragma unroll 1
    for (int j = 0; j < nj; ++j) {
      __syncthreads();
      if (j + 1 < nj) stage(cur ^ 1, (j + 1) * 64);
      const char* KsB = (const char*)&Ks[cur][0];
      const char* VsB = (const char*)&Vs[cur][0];
      int kb = j * 64;
      f32x4 s[4];
#pragma unroll
      for (int ntl = 0; ntl < 4; ++ntl) {
        s[ntl] = zero;
        int rowb = (ntl * 16 + mr) * 256;
#pragma unroll
        for (int db = 0; db < 4; ++db) {
          bf16x8 kf = *(const bf16x8*)(KsB + rowb + ((db * 64 + kg * 16) ^ swz));
          s[ntl] = MFMA16(qf[db], kf, s[ntl]);
        }
      }
      float pvv[4][4];
      float tmax[4] = {-3e38f, -3e38f, -3e38f, -3e38f};
      bool diag = (j == qb);
#pragma unroll
      for (int ntl = 0; ntl < 4; ++ntl)
#pragma unroll
        for (int jj = 0; jj < 4; ++jj) {
          float v = s[ntl][jj] * cscale;
          if (diag && (kb + ntl * 16 + mr) > (qr0 + kg * 4 + jj)) v = -1e30f;
          pvv[ntl][jj] = v;
          tmax[jj] = fmaxf(tmax[jj], v);
        }
#pragma unroll
      for (int m = 1; m < 16; m <<= 1)
#pragma unroll
        for (int jj = 0; jj < 4; ++jj)
          tmax[jj] = fmaxf(tmax[jj], __shfl_xor(tmax[jj], m, 64));
      bool ok = true;
#pragma unroll
      for (int jj = 0; jj < 4; ++jj) ok &= (tmax[jj] <= mrun[jj] + 8.0f);
      if (!__all(ok)) {
#pragma unroll
        for (int jj = 0; jj < 4; ++jj) {
          float mn = fmaxf(mrun[jj], tmax[jj]);
          float corr = __builtin_amdgcn_exp2f(mrun[jj] - mn);
          mrun[jj] = mn;
          lrun[jj] *= corr;
#pragma unroll
          for (int d2 = 0; d2 < 8; ++d2) acc[d2][jj] *= corr;
        }
      }
      float rs[4] = {0.f, 0.f, 0.f, 0.f};
#pragma unroll
      for (int ntl = 0; ntl < 4; ++ntl)
#pragma unroll
        for (int jj = 0; jj < 4; ++jj) {
          float p = __builtin_amdgcn_exp2f(pvv[ntl][jj] - mrun[jj]);
          pvv[ntl][jj] = p;
          rs[jj] += p;
        }
#pragma unroll
      for (int m = 1; m < 16; m <<= 1)
#pragma unroll
        for (int jj = 0; jj < 4; ++jj) rs[jj] += __shfl_xor(rs[jj], m, 64);
#pragma unroll
      for (int jj = 0; jj < 4; ++jj) lrun[jj] += rs[jj];
#pragma unroll
      for (int ntl = 0; ntl < 4; ++ntl)
#pragma unroll
        for (int jj = 0; jj < 4; ++jj) {
          int rr = kg * 4 + jj;
          int cbyte = (mr + ntl * 16) * 2;
          *(bf16_t*)((char*)P + rr * 128 + (cbyte ^ ((rr & 7) << 4))) = (bf16_t)pvv[ntl][jj];
        }
#pragma unroll
      for (int ks = 0; ks < 2; ++ks) {
        int cb = (ks * 32 + kg * 8) * 2;
        bf16x8 pa = *(const bf16x8*)((const char*)P + mr * 128 + (cb ^ ((mr & 7) << 4)));
#pragma unroll
        for (int d2 = 0; d2 < 8; ++d2) {
          bf16x8 vf = *(const bf16x8*)(VsB + (d2 * 16 + mr) * 128 + ((ks * 64 + kg * 16) ^ swz));
          acc[d2] = MFMA16(pa, vf, acc[d2]);
        }
      }
      cur ^= 1;
    }
#pragma unroll
    for (int jj = 0; jj < 4; ++jj) {
      float invl = 1.0f / lrun[jj];
      int t = qr0 + kg * 4 + jj;
      size_t row = (size_t)b * 2048 + h * 128 + (t >> 4);
      bf16_t* orow = og + row * 2048 + (t & 15) * 128;
#pragma unroll
      for (int d2 = 0; d2 < 8; ++d2)
        orow[d2 * 16 + mr] = (bf16_t)(acc[d2][jj] * invl);
    }
  }
}

extern "C" void kernel_launch(void* const* d_in, const int* in_sizes, int n_in,
                              void* d_out, int out_size, void* d_ws, size_t ws_size,
                              hipStream_t stream) {
  const float* x = (const float*)d_in[0];      // [2,2048,2048]
  const float* wqkv = (const float*)d_in[1];   // [6144,2048]
  const float* wproj = (const float*)d_in[2];  // [2048,2048]
  float* out = (float*)d_out;                  // [2,2048,2048]
  char* ws = (char*)d_ws;

  const size_t OFF_WQKV = 16777216;
  const size_t OFF_Q = 41943040;
  const size_t OFF_K = 58720256;
  const size_t OFF_VT = 75497472;

  bf16_t* xb = (bf16_t*)(ws);
  bf16_t* wqkvb = (bf16_t*)(ws + OFF_WQKV);
  bf16_t* g_q = (bf16_t*)(ws + OFF_Q);
  bf16_t* g_k = (bf16_t*)(ws + OFF_K);
  bf16_t* g_vt = (bf16_t*)(ws + OFF_VT);
  bf16_t* g_att = (bf16_t*)(ws);               // alias xb (dead after gemm1)
  bf16_t* wprojb = (bf16_t*)(ws + OFF_WQKV);   // alias wqkvb (dead after gemm1)

  cast_f32_bf16<<<2048, 256, 0, stream>>>(x, xb, 8388608 / 8);
  cast_f32_bf16<<<2048, 256, 0, stream>>>(wqkv, wqkvb, 12582912 / 8);
  // qkv gemm (256x128 tiles, 768 blocks = 3 full CU rounds) + fused RoPE/V^T epilogue
  gemm256<1><<<768, 512, 0, stream>>>(xb, wqkvb, nullptr, g_q, g_k, g_vt,
                                      4096, 6144, 2048, 16);
  cast_f32_bf16<<<2048, 256, 0, stream>>>(wproj, wprojb, 4194304 / 8);
  attn_kernel<<<dim3(16, 32), 256, 0, stream>>>(g_q, g_k, g_vt, g_att);
  // output projection (256 blocks = 1 full CU round)
  gemm256<0><<<256, 512, 0, stream>>>(g_att, wprojb, out, nullptr, nullptr, nullptr,
                                      4096, 2048, 2048, 16);
}

// Round 6
// 277.730 us; speedup vs baseline: 1.0301x; 1.0301x over previous
//
#include <hip/hip_runtime.h>
#include <hip/hip_bf16.h>

typedef __bf16 bf16_t;
typedef __bf16 bf16x8 __attribute__((ext_vector_type(8)));
typedef float f32x4 __attribute__((ext_vector_type(4)));

#define MFMA16(a, b, c) __builtin_amdgcn_mfma_f32_16x16x32_bf16(a, b, c, 0, 0, 0)

__device__ __forceinline__ void async_copy16(const void* g, void* l) {
  __builtin_amdgcn_global_load_lds(
      (const __attribute__((address_space(1))) void*)g,
      (__attribute__((address_space(3))) void*)l, 16, 0, 0);
}

// ---------------- cast f32 -> bf16 (8 elems/thread) ----------------
__global__ void cast_f32_bf16(const float* __restrict__ in, bf16_t* __restrict__ out, int n8) {
  int stride = gridDim.x * blockDim.x;
  for (int i = blockIdx.x * blockDim.x + threadIdx.x; i < n8; i += stride) {
    const float* p = in + (size_t)i * 8;
    f32x4 a = *(const f32x4*)p;
    f32x4 b = *(const f32x4*)(p + 4);
    bf16x8 o;
    o[0] = (bf16_t)a[0]; o[1] = (bf16_t)a[1]; o[2] = (bf16_t)a[2]; o[3] = (bf16_t)a[3];
    o[4] = (bf16_t)b[0]; o[5] = (bf16_t)b[1]; o[6] = (bf16_t)b[2]; o[7] = (bf16_t)b[3];
    *(bf16x8*)(out + (size_t)i * 8) = o;
  }
}

// ------- GEMM 256x128 tile, BK=64, 512 thr (8 waves 4Mx2N), depth-2 prefetch -------
// 3-buffer rotation: iter t stages tile t+2, computes tile t, waits vmcnt(6) once
// (confirms tile t+1, issued a FULL iteration ago), single barrier per iter.
// C[m][n] = sum_k A[m][k] * Bw[n][k] (both K-major bf16)
// MODE 0: write f32 C row-major [M][N]
// MODE 1: fused epilogue via LDS roundtrip (RoPE for q/k, transpose for V)
template <int MODE>
__global__ __launch_bounds__(512, 2) void gemm256(
    const bf16_t* __restrict__ A, const bf16_t* __restrict__ Bw, float* __restrict__ C,
    bf16_t* __restrict__ qo, bf16_t* __restrict__ ko, bf16_t* __restrict__ vto,
    int M, int N, int K, int nby) {
  // per buffer (48KB): A 256x64 bf16 @ +0 (32KB), B 128x64 bf16 @ +32768 (16KB); x3 buffers
  __shared__ __align__(16) char lds[147456];
  int tid = threadIdx.x;
  int w = tid >> 6, lane = tid & 63;
  int wm = w >> 1, wn = w & 1;
  int mr = lane & 15, kg = lane >> 4;

  // bijective XCD chunking + col-major decompose (B-panel L2 locality)
  int nwg = gridDim.x;
  int orig = blockIdx.x;
  int wgid = (orig & 7) * (nwg >> 3) + (orig >> 3);
  int by = wgid % nby, bx = wgid / nby;
  int row0 = by * 256, col0 = bx * 128;

  // staging source offsets: inverse-swizzled global (rule #21), linear LDS dest
  size_t aoff[4], boff[2];
#pragma unroll
  for (int it = 0; it < 4; ++it) {
    int c = tid + it * 512;
    int r = c >> 3;
    int chs = (c & 7) ^ (r & 7);
    aoff[it] = (size_t)(row0 + r) * K + chs * 8;
  }
#pragma unroll
  for (int it = 0; it < 2; ++it) {
    int c = tid + it * 512;
    int r = c >> 3;
    int chs = (c & 7) ^ (r & 7);
    boff[it] = (size_t)(col0 + r) * K + chs * 8;
  }

  auto stageA = [&](int buf, int kt, int half) {  // 2 loads
    char* Ad = &lds[buf * 49152];
#pragma unroll
    for (int it = half * 2; it < half * 2 + 2; ++it)
      async_copy16(A + aoff[it] + kt * 64, Ad + (tid + it * 512) * 16);
  };
  auto stageB = [&](int buf, int kt) {  // 2 loads
    char* Bd = &lds[buf * 49152 + 32768];
#pragma unroll
    for (int it = 0; it < 2; ++it)
      async_copy16(Bw + boff[it] + kt * 64, Bd + (tid + it * 512) * 16);
  };

  f32x4 zero = {0.f, 0.f, 0.f, 0.f};
  f32x4 acc[4][4];
#pragma unroll
  for (int mi = 0; mi < 4; ++mi)
#pragma unroll
    for (int ni = 0; ni < 4; ++ni) acc[mi][ni] = zero;

  int nt = K >> 6;  // 32
  // prologue: tiles 0,1 staged; wait tile 0; invariant: tile 1's 6 loads in flight
  stageA(0, 0, 0); stageA(0, 0, 1); stageB(0, 0);
  stageA(1, 1, 0); stageA(1, 1, 1); stageB(1, 1);
  asm volatile("s_waitcnt vmcnt(6)" ::: "memory");
  __builtin_amdgcn_sched_barrier(0);
  __builtin_amdgcn_s_barrier();
  __builtin_amdgcn_sched_barrier(0);

#pragma unroll 1
  for (int t = 0; t < nt; ++t) {
    int cur = t % 3;
    int nxt = (t + 2) % 3;
    int kt2 = (t + 2 < nt) ? (t + 2) : t;  // tail: harmless dummy restage
    const char* Ab = &lds[cur * 49152];
    const char* Bb = &lds[cur * 49152 + 32768];
    bf16x8 af[4][2], bfr[4][2];
#pragma unroll
    for (int mi = 0; mi < 4; ++mi) {
      int row = wm * 64 + mi * 16 + mr;
      const char* rb = Ab + row * 128;
      int sz = (row & 7) << 4;
      af[mi][0] = *(const bf16x8*)(rb + ((kg * 16) ^ sz));
      af[mi][1] = *(const bf16x8*)(rb + ((64 + kg * 16) ^ sz));
    }
#pragma unroll
    for (int ni = 0; ni < 4; ++ni) {
      int row = wn * 64 + ni * 16 + mr;
      const char* rb = Bb + row * 128;
      int sz = (row & 7) << 4;
      bfr[ni][0] = *(const bf16x8*)(rb + ((kg * 16) ^ sz));
      bfr[ni][1] = *(const bf16x8*)(rb + ((64 + kg * 16) ^ sz));
    }
    // fine interleave: stage pairs of tile t+2 between MFMA quadrant clusters
    stageA(nxt, kt2, 0);
    __builtin_amdgcn_s_setprio(1);
#pragma unroll
    for (int mi = 0; mi < 4; ++mi) {
      acc[mi][0] = MFMA16(af[mi][0], bfr[0][0], acc[mi][0]);
      acc[mi][0] = MFMA16(af[mi][1], bfr[0][1], acc[mi][0]);
    }
    __builtin_amdgcn_s_setprio(0);
    stageA(nxt, kt2, 1);
    __builtin_amdgcn_s_setprio(1);
#pragma unroll
    for (int mi = 0; mi < 4; ++mi) {
      acc[mi][1] = MFMA16(af[mi][0], bfr[1][0], acc[mi][1]);
      acc[mi][1] = MFMA16(af[mi][1], bfr[1][1], acc[mi][1]);
    }
    __builtin_amdgcn_s_setprio(0);
    stageB(nxt, kt2);
    __builtin_amdgcn_s_setprio(1);
#pragma unroll
    for (int mi = 0; mi < 4; ++mi) {
      acc[mi][2] = MFMA16(af[mi][0], bfr[2][0], acc[mi][2]);
      acc[mi][2] = MFMA16(af[mi][1], bfr[2][1], acc[mi][2]);
      acc[mi][3] = MFMA16(af[mi][0], bfr[3][0], acc[mi][3]);
      acc[mi][3] = MFMA16(af[mi][1], bfr[3][1], acc[mi][3]);
    }
    __builtin_amdgcn_s_setprio(0);
    // single counted wait + barrier per iter: confirms tile t+1 (issued iter t-1),
    // leaves tile t+2's 6 loads in flight; closes buf[cur] reads before iter t+1
    // overwrites buf[(t+3)%3] == buf[cur].
    asm volatile("s_waitcnt vmcnt(6)" ::: "memory");
    __builtin_amdgcn_sched_barrier(0);
    __builtin_amdgcn_s_barrier();
    __builtin_amdgcn_sched_barrier(0);
  }
  asm volatile("s_waitcnt vmcnt(0)" ::: "memory");
  __syncthreads();

  if (MODE == 0) {
#pragma unroll
    for (int mi = 0; mi < 4; ++mi)
#pragma unroll
      for (int ni = 0; ni < 4; ++ni)
#pragma unroll
        for (int jj = 0; jj < 4; ++jj) {
          int row = row0 + wm * 64 + mi * 16 + kg * 4 + jj;
          int col = col0 + wn * 64 + ni * 16 + mr;
          C[(size_t)row * N + col] = acc[mi][ni][jj];
        }
  } else {
    char* tb = &lds[0];  // 64KB as 256x128 bf16 tile, 256B rows
    int s = col0 >> 11, h = (col0 >> 7) & 15;
    int b = row0 >> 11, t0 = row0 & 2047;
    if (s < 2) {
      // ---- q/k: [t(256)][d(128)] bf16, swizzled ----
#pragma unroll
      for (int mi = 0; mi < 4; ++mi)
#pragma unroll
        for (int ni = 0; ni < 4; ++ni)
#pragma unroll
          for (int jj = 0; jj < 4; ++jj) {
            int rloc = wm * 64 + mi * 16 + kg * 4 + jj;
            int cb = (wn * 64 + ni * 16 + mr) * 2;
            *(bf16_t*)(tb + rloc * 256 + (cb ^ ((rloc & 7) << 4))) = (bf16_t)acc[mi][ni][jj];
          }
      __syncthreads();
      // ---- read half-row, apply RoPE, store contiguous ----
      int r = tid >> 1, hh = tid & 1;
      const char* rowb = tb + r * 256;
      int sz = (r & 7) << 4;
      int t = t0 + r;
      bf16_t* dst = (s == 0 ? qo : ko) + ((size_t)((b * 16 + h) * 2048 + t)) * 128 + hh * 64;
      float tf = (float)t;
      const float cinv = -0.20762050593046014f;  // -log2(10000)/64
#pragma unroll
      for (int m = 0; m < 8; ++m) {
        bf16x8 va = *(const bf16x8*)(rowb + ((hh * 128 + m * 16) ^ sz));
        bf16x8 vb = *(const bf16x8*)(rowb + (((hh ^ 1) * 128 + m * 16) ^ sz));
        bf16x8 o;
#pragma unroll
        for (int e = 0; e < 8; ++e) {
          float ang = tf * exp2f((float)(m * 8 + e) * cinv);
          float sv = __sinf(ang), cv = __cosf(ang);
          float x1 = (float)va[e], x2 = (float)vb[e];
          o[e] = (bf16_t)((hh == 0) ? (x1 * cv - x2 * sv) : (x1 * cv + x2 * sv));
        }
        *(bf16x8*)(dst + m * 8) = o;
      }
    } else {
      // ---- v: transposed [d(128)][t(256)] bf16, 512B rows, swizzled ----
#pragma unroll
      for (int mi = 0; mi < 4; ++mi)
#pragma unroll
        for (int ni = 0; ni < 4; ++ni)
#pragma unroll
          for (int jj = 0; jj < 4; ++jj) {
            int rloc = wm * 64 + mi * 16 + kg * 4 + jj;   // t
            int cloc = wn * 64 + ni * 16 + mr;            // d
            *(bf16_t*)(tb + cloc * 512 + ((rloc * 2) ^ ((cloc & 7) << 4))) =
                (bf16_t)acc[mi][ni][jj];
          }
      __syncthreads();
      int d = tid >> 2, qt = tid & 3;
      const char* rowb = tb + d * 512;
      int sz = (d & 7) << 4;
      bf16_t* dst = vto + ((size_t)((b * 16 + h) * 128 + d)) * 2048 + t0 + qt * 64;
#pragma unroll
      for (int m2 = 0; m2 < 8; ++m2)
        *(bf16x8*)(dst + m2 * 8) = *(const bf16x8*)(rowb + ((qt * 128 + m2 * 16) ^ sz));
    }
  }
}

// ---------------- causal flash attention (v2, unchanged) ----------------
__global__ __launch_bounds__(256) void attn_kernel(
    const bf16_t* __restrict__ qg, const bf16_t* __restrict__ kgl,
    const bf16_t* __restrict__ vtg, bf16_t* __restrict__ og) {
  __shared__ __align__(16) bf16_t Ks[2][64 * 128];
  __shared__ __align__(16) bf16_t Vs[2][128 * 64];
  __shared__ __align__(16) bf16_t plds[4][1024];
  const int T = 2048;
  int tid = threadIdx.x;
  int w = tid >> 6, lane = tid & 63;
  int mr = lane & 15, kg = lane >> 4;
  int swz = (mr & 7) << 4;

  int L = blockIdx.y * 16 + blockIdx.x;
  int role = (L & 7) * 64 + (L >> 3);
  int bx = role & 15, bh = role >> 4;

  const bf16_t* Q = qg + (size_t)bh * T * 128;
  const bf16_t* K = kgl + (size_t)bh * T * 128;
  const bf16_t* Vt = vtg + (size_t)bh * 128 * T;

  int sb = tid * 16;
  int krl = sb >> 8;
  int kc = (sb & 255) ^ ((krl & 7) << 4);
  size_t ksrc = (size_t)krl * 128 + (kc >> 1);
  int vdl = sb >> 7;
  int vc = (sb & 127) ^ ((vdl & 7) << 4);
  size_t vsrc = (size_t)vdl * 2048 + (vc >> 1);

  auto stage = [&](int buf, int kb) {
#pragma unroll
    for (int it = 0; it < 4; ++it)
      async_copy16(K + (size_t)(kb + it * 16) * 128 + ksrc, &Ks[buf][it * 2048 + tid * 8]);
#pragma unroll
    for (int it = 0; it < 4; ++it)
      async_copy16(Vt + (size_t)it * 65536 + kb + vsrc, &Vs[buf][it * 2048 + tid * 8]);
  };

  const float cscale = 0.12751744f;  // (1/sqrt(128)) * log2(e)
  f32x4 zero = {0.f, 0.f, 0.f, 0.f};
  bf16_t* P = &plds[w][0];
  int b = bh >> 4, h = bh & 15;

#pragma unroll 1
  for (int ph = 0; ph < 2; ++ph) {
    int qb = ph ? bx : (31 - bx);
    int qr0 = qb * 64 + w * 16;
    bf16x8 qf[4];
#pragma unroll
    for (int db = 0; db < 4; ++db)
      qf[db] = *(const bf16x8*)(Q + (size_t)(qr0 + mr) * 128 + db * 32 + kg * 8);

    f32x4 acc[8];
#pragma unroll
    for (int d2 = 0; d2 < 8; ++d2) acc[d2] = zero;
    float mrun[4] = {-1e30f, -1e30f, -1e30f, -1e30f};
    float lrun[4] = {0.f, 0.f, 0.f, 0.f};

    int nj = qb + 1;
    __syncthreads();
    stage(0, 0);
    int cur = 0;
#pragma unroll 1
    for (int j = 0; j < nj; ++j) {
      __syncthreads();
      if (j + 1 < nj) stage(cur ^ 1, (j + 1) * 64);
      const char* KsB = (const char*)&Ks[cur][0];
      const char* VsB = (const char*)&Vs[cur][0];
      int kb = j * 64;
      f32x4 s[4];
#pragma unroll
      for (int ntl = 0; ntl < 4; ++ntl) {
        s[ntl] = zero;
        int rowb = (ntl * 16 + mr) * 256;
#pragma unroll
        for (int db = 0; db < 4; ++db) {
          bf16x8 kf = *(const bf16x8*)(KsB + rowb + ((db * 64 + kg * 16) ^ swz));
          s[ntl] = MFMA16(qf[db], kf, s[ntl]);
        }
      }
      float pvv[4][4];
      float tmax[4] = {-3e38f, -3e38f, -3e38f, -3e38f};
      bool diag = (j == qb);
#pragma unroll
      for (int ntl = 0; ntl < 4; ++ntl)
#pragma unroll
        for (int jj = 0; jj < 4; ++jj) {
          float v = s[ntl][jj] * cscale;
          if (diag && (kb + ntl * 16 + mr) > (qr0 + kg * 4 + jj)) v = -1e30f;
          pvv[ntl][jj] = v;
          tmax[jj] = fmaxf(tmax[jj], v);
        }
#pragma unroll
      for (int m = 1; m < 16; m <<= 1)
#pragma unroll
        for (int jj = 0; jj < 4; ++jj)
          tmax[jj] = fmaxf(tmax[jj], __shfl_xor(tmax[jj], m, 64));
      bool ok = true;
#pragma unroll
      for (int jj = 0; jj < 4; ++jj) ok &= (tmax[jj] <= mrun[jj] + 8.0f);
      if (!__all(ok)) {
#pragma unroll
        for (int jj = 0; jj < 4; ++jj) {
          float mn = fmaxf(mrun[jj], tmax[jj]);
          float corr = __builtin_amdgcn_exp2f(mrun[jj] - mn);
          mrun[jj] = mn;
          lrun[jj] *= corr;
#pragma unroll
          for (int d2 = 0; d2 < 8; ++d2) acc[d2][jj] *= corr;
        }
      }
      float rs[4] = {0.f, 0.f, 0.f, 0.f};
#pragma unroll
      for (int ntl = 0; ntl < 4; ++ntl)
#pragma unroll
        for (int jj = 0; jj < 4; ++jj) {
          float p = __builtin_amdgcn_exp2f(pvv[ntl][jj] - mrun[jj]);
          pvv[ntl][jj] = p;
          rs[jj] += p;
        }
#pragma unroll
      for (int m = 1; m < 16; m <<= 1)
#pragma unroll
        for (int jj = 0; jj < 4; ++jj) rs[jj] += __shfl_xor(rs[jj], m, 64);
#pragma unroll
      for (int jj = 0; jj < 4; ++jj) lrun[jj] += rs[jj];
#pragma unroll
      for (int ntl = 0; ntl < 4; ++ntl)
#pragma unroll
        for (int jj = 0; jj < 4; ++jj) {
          int rr = kg * 4 + jj;
          int cbyte = (mr + ntl * 16) * 2;
          *(bf16_t*)((char*)P + rr * 128 + (cbyte ^ ((rr & 7) << 4))) = (bf16_t)pvv[ntl][jj];
        }
#pragma unroll
      for (int ks = 0; ks < 2; ++ks) {
        int cb = (ks * 32 + kg * 8) * 2;
        bf16x8 pa = *(const bf16x8*)((const char*)P + mr * 128 + (cb ^ ((mr & 7) << 4)));
#pragma unroll
        for (int d2 = 0; d2 < 8; ++d2) {
          bf16x8 vf = *(const bf16x8*)(VsB + (d2 * 16 + mr) * 128 + ((ks * 64 + kg * 16) ^ swz));
          acc[d2] = MFMA16(pa, vf, acc[d2]);
        }
      }
      cur ^= 1;
    }
#pragma unroll
    for (int jj = 0; jj < 4; ++jj) {
      float invl = 1.0f / lrun[jj];
      int t = qr0 + kg * 4 + jj;
      size_t row = (size_t)b * 2048 + h * 128 + (t >> 4);
      bf16_t* orow = og + row * 2048 + (t & 15) * 128;
#pragma unroll
      for (int d2 = 0; d2 < 8; ++d2)
        orow[d2 * 16 + mr] = (bf16_t)(acc[d2][jj] * invl);
    }
  }
}

extern "C" void kernel_launch(void* const* d_in, const int* in_sizes, int n_in,
                              void* d_out, int out_size, void* d_ws, size_t ws_size,
                              hipStream_t stream) {
  const float* x = (const float*)d_in[0];      // [2,2048,2048]
  const float* wqkv = (const float*)d_in[1];   // [6144,2048]
  const float* wproj = (const float*)d_in[2];  // [2048,2048]
  float* out = (float*)d_out;                  // [2,2048,2048]
  char* ws = (char*)d_ws;

  const size_t OFF_WQKV = 16777216;
  const size_t OFF_Q = 41943040;
  const size_t OFF_K = 58720256;
  const size_t OFF_VT = 75497472;

  bf16_t* xb = (bf16_t*)(ws);
  bf16_t* wqkvb = (bf16_t*)(ws + OFF_WQKV);
  bf16_t* g_q = (bf16_t*)(ws + OFF_Q);
  bf16_t* g_k = (bf16_t*)(ws + OFF_K);
  bf16_t* g_vt = (bf16_t*)(ws + OFF_VT);
  bf16_t* g_att = (bf16_t*)(ws);               // alias xb (dead after gemm1)
  bf16_t* wprojb = (bf16_t*)(ws + OFF_WQKV);   // alias wqkvb (dead after gemm1)

  cast_f32_bf16<<<2048, 256, 0, stream>>>(x, xb, 8388608 / 8);
  cast_f32_bf16<<<2048, 256, 0, stream>>>(wqkv, wqkvb, 12582912 / 8);
  // qkv gemm (256x128 tiles, 768 blocks = 3 full CU rounds) + fused RoPE/V^T epilogue
  gemm256<1><<<768, 512, 0, stream>>>(xb, wqkvb, nullptr, g_q, g_k, g_vt,
                                      4096, 6144, 2048, 16);
  cast_f32_bf16<<<2048, 256, 0, stream>>>(wproj, wprojb, 4194304 / 8);
  attn_kernel<<<dim3(16, 32), 256, 0, stream>>>(g_q, g_k, g_vt, g_att);
  // output projection (256 blocks = 1 full CU round)
  gemm256<0><<<256, 512, 0, stream>>>(g_att, wprojb, out, nullptr, nullptr, nullptr,
                                      4096, 2048, 2048, 16);
}

// Round 7
// 277.473 us; speedup vs baseline: 1.0310x; 1.0009x over previous
//
#include <hip/hip_runtime.h>
#include <hip/hip_bf16.h>

typedef __bf16 bf16_t;
typedef __bf16 bf16x8 __attribute__((ext_vector_type(8)));
typedef float f32x4 __attribute__((ext_vector_type(4)));

#define MFMA16(a, b, c) __builtin_amdgcn_mfma_f32_16x16x32_bf16(a, b, c, 0, 0, 0)

__device__ __forceinline__ void async_copy16(const void* g, void* l) {
  __builtin_amdgcn_global_load_lds(
      (const __attribute__((address_space(1))) void*)g,
      (__attribute__((address_space(3))) void*)l, 16, 0, 0);
}

// ---------------- cast f32 -> bf16 (8 elems/thread) ----------------
__global__ void cast_f32_bf16(const float* __restrict__ in, bf16_t* __restrict__ out, int n8) {
  int stride = gridDim.x * blockDim.x;
  for (int i = blockIdx.x * blockDim.x + threadIdx.x; i < n8; i += stride) {
    const float* p = in + (size_t)i * 8;
    f32x4 a = *(const f32x4*)p;
    f32x4 b = *(const f32x4*)(p + 4);
    bf16x8 o;
    o[0] = (bf16_t)a[0]; o[1] = (bf16_t)a[1]; o[2] = (bf16_t)a[2]; o[3] = (bf16_t)a[3];
    o[4] = (bf16_t)b[0]; o[5] = (bf16_t)b[1]; o[6] = (bf16_t)b[2]; o[7] = (bf16_t)b[3];
    *(bf16x8*)(out + (size_t)i * 8) = o;
  }
}

// ======== GEMM1 (QKV): 256x256 tile, BK=32, 512 thr (8 waves 2Mx4N, wave=128x64) ========
// depth-3 prefetch, 4-buffer rotation, vmcnt(8) counted wait, fused RoPE/V^T epilogue.
// grid 384 = 16(by) x 24(bx); XCD 2D chunks 4x12, by-fastest inside.
__global__ __launch_bounds__(512, 2) void gemm_qkv(
    const bf16_t* __restrict__ A, const bf16_t* __restrict__ Bw,
    bf16_t* __restrict__ qo, bf16_t* __restrict__ ko, bf16_t* __restrict__ vto,
    int K) {
  __shared__ __align__(16) char lds[131072];  // 4 buf x (A 16KB + B 16KB)
  int tid = threadIdx.x;
  int w = tid >> 6, lane = tid & 63;
  int wm = w & 1, wn = w >> 1;
  int mr = lane & 15, kg = lane >> 4;

  // XCD chunking: chunk rect 4(by) x 12(bx); by-fastest within chunk
  int orig = blockIdx.x;
  int chunk = orig & 7, i = orig >> 3;
  int by = (chunk & 3) * 4 + (i & 3);
  int bx = (chunk >> 2) * 12 + (i >> 2);
  int row0 = by * 256, col0 = bx * 256;

  // staging: linear LDS dest, inverse-swizzled global source
  // dest byte D = c*16 (c = tid + it*512): r = c>>2, phys chunk = c&3,
  // logical k-chunk = (c&3) ^ ((r>>1)&3)
  size_t aoff[2], boff[2];
#pragma unroll
  for (int it = 0; it < 2; ++it) {
    int c = tid + it * 512;
    int r = c >> 2;
    int lc = (c & 3) ^ ((r >> 1) & 3);
    aoff[it] = (size_t)(row0 + r) * K + lc * 8;
    boff[it] = (size_t)(col0 + r) * K + lc * 8;
  }

  auto stageA = [&](int buf, int kt) {
    char* Ad = &lds[buf * 32768];
#pragma unroll
    for (int it = 0; it < 2; ++it)
      async_copy16(A + aoff[it] + kt * 32, Ad + (tid + it * 512) * 16);
  };
  auto stageB = [&](int buf, int kt) {
    char* Bd = &lds[buf * 32768 + 16384];
#pragma unroll
    for (int it = 0; it < 2; ++it)
      async_copy16(Bw + boff[it] + kt * 32, Bd + (tid + it * 512) * 16);
  };

  f32x4 zero = {0.f, 0.f, 0.f, 0.f};
  f32x4 acc[8][4];
#pragma unroll
  for (int mi = 0; mi < 8; ++mi)
#pragma unroll
    for (int ni = 0; ni < 4; ++ni) acc[mi][ni] = zero;

  int nt = K >> 5;  // 64
  // prologue: stage tiles 0,1,2; confirm tile 0 (leave 8 in flight)
  stageA(0, 0); stageB(0, 0);
  stageA(1, 1); stageB(1, 1);
  stageA(2, 2); stageB(2, 2);
  asm volatile("s_waitcnt vmcnt(8)" ::: "memory");
  __builtin_amdgcn_sched_barrier(0);
  __builtin_amdgcn_s_barrier();
  __builtin_amdgcn_sched_barrier(0);

#pragma unroll 1
  for (int t = 0; t < nt; ++t) {
    int cur = t & 3;
    int nb = (t + 3) & 3;
    int kt3 = (t + 3 < nt) ? (t + 3) : (nt - 1);  // tail: dummy restage, unread buffer
    const char* Ab = &lds[cur * 32768];
    const char* Bb = &lds[cur * 32768 + 16384];
    bf16x8 af[8], bfr[4];
#pragma unroll
    for (int mi = 0; mi < 8; ++mi) {
      int r = wm * 128 + mi * 16 + mr;
      af[mi] = *(const bf16x8*)(Ab + r * 64 + ((kg ^ ((r >> 1) & 3)) << 4));
    }
#pragma unroll
    for (int ni = 0; ni < 4; ++ni) {
      int r = wn * 64 + ni * 16 + mr;
      bfr[ni] = *(const bf16x8*)(Bb + r * 64 + ((kg ^ ((r >> 1) & 3)) << 4));
    }
    // interleave: stage pairs of tile t+3 between MFMA ni-clusters
    stageA(nb, kt3);
    __builtin_amdgcn_s_setprio(1);
#pragma unroll
    for (int mi = 0; mi < 8; ++mi) acc[mi][0] = MFMA16(af[mi], bfr[0], acc[mi][0]);
#pragma unroll
    for (int mi = 0; mi < 8; ++mi) acc[mi][1] = MFMA16(af[mi], bfr[1], acc[mi][1]);
    __builtin_amdgcn_s_setprio(0);
    stageB(nb, kt3);
    __builtin_amdgcn_s_setprio(1);
#pragma unroll
    for (int mi = 0; mi < 8; ++mi) acc[mi][2] = MFMA16(af[mi], bfr[2], acc[mi][2]);
#pragma unroll
    for (int mi = 0; mi < 8; ++mi) acc[mi][3] = MFMA16(af[mi], bfr[3], acc[mi][3]);
    __builtin_amdgcn_s_setprio(0);
    // counted wait: outstanding = t+2 (4) + t+3 (4) = 8 -> tile t+1 confirmed
    asm volatile("s_waitcnt vmcnt(8)" ::: "memory");
    __builtin_amdgcn_sched_barrier(0);
    __builtin_amdgcn_s_barrier();
    __builtin_amdgcn_sched_barrier(0);
  }
  asm volatile("s_waitcnt vmcnt(0)" ::: "memory");
  __syncthreads();

  // ---- fused epilogue via LDS roundtrip (tile = 256 x 256 = 128 KB) ----
  char* tb = &lds[0];
  int s = col0 >> 11;               // 0:q 1:k 2:v
  int h0 = (col0 >> 7) & 15;        // first of two heads in this block
  int b = row0 >> 11, t0 = row0 & 2047;
  if (s < 2) {
    // q/k: [t(256)][d(256) = 2 heads x 128] bf16, 512B rows, chunk-swizzled
#pragma unroll
    for (int mi = 0; mi < 8; ++mi)
#pragma unroll
      for (int ni = 0; ni < 4; ++ni)
#pragma unroll
        for (int jj = 0; jj < 4; ++jj) {
          int rl = wm * 128 + mi * 16 + kg * 4 + jj;
          int cb = (wn * 64 + ni * 16 + mr) * 2;
          *(bf16_t*)(tb + rl * 512 + (cb ^ ((rl & 7) << 4))) = (bf16_t)acc[mi][ni][jj];
        }
    __syncthreads();
    // each thread: one (row, head) pair -> RoPE over 128 elems, contiguous store
    int r = tid >> 1, hs = tid & 1;
    const char* rowb = tb + r * 512;
    int sz = (r & 7) << 4;
    int t = t0 + r;
    bf16_t* dst = (s == 0 ? qo : ko) + ((size_t)((b * 16 + h0 + hs) * 2048 + t)) * 128;
    float tf = (float)t;
    const float cinv = -0.20762050593046014f;  // -log2(10000)/64
    bf16x8 vin[16];
#pragma unroll
    for (int m = 0; m < 16; ++m)
      vin[m] = *(const bf16x8*)(rowb + ((hs * 256 + m * 16) ^ sz));
#pragma unroll
    for (int m = 0; m < 8; ++m) {
      bf16x8 o1, o2;
#pragma unroll
      for (int e = 0; e < 8; ++e) {
        float ang = tf * exp2f((float)(m * 8 + e) * cinv);
        float sv = __sinf(ang), cv = __cosf(ang);
        float x1 = (float)vin[m][e], x2 = (float)vin[m + 8][e];
        o1[e] = (bf16_t)(x1 * cv - x2 * sv);
        o2[e] = (bf16_t)(x2 * cv + x1 * sv);
      }
      *(bf16x8*)(dst + m * 8) = o1;
      *(bf16x8*)(dst + 64 + m * 8) = o2;
    }
  } else {
    // v: transposed [d(256)][t(256)] bf16, 512B rows, chunk-swizzled
#pragma unroll
    for (int mi = 0; mi < 8; ++mi)
#pragma unroll
      for (int ni = 0; ni < 4; ++ni)
#pragma unroll
        for (int jj = 0; jj < 4; ++jj) {
          int rl = wm * 128 + mi * 16 + kg * 4 + jj;   // t
          int cl = wn * 64 + ni * 16 + mr;             // d (0..255)
          *(bf16_t*)(tb + cl * 512 + ((rl * 2) ^ ((cl & 7) << 4))) = (bf16_t)acc[mi][ni][jj];
        }
    __syncthreads();
    int d = tid >> 1, ts = tid & 1;
    const char* rowb = tb + d * 512;
    int sz = (d & 7) << 4;
    bf16_t* dst = vto + ((size_t)((b * 16 + h0 + (d >> 7)) * 128 + (d & 127))) * 2048 +
                  t0 + ts * 128;
#pragma unroll
    for (int m = 0; m < 16; ++m)
      *(bf16x8*)(dst + m * 8) = *(const bf16x8*)(rowb + ((ts * 256 + m * 16) ^ sz));
  }
}

// ------- GEMM2: 256x128 tile, BK=64, 512 thr, depth-2 (proven R6 structure) -------
template <int MODE>
__global__ __launch_bounds__(512, 2) void gemm256(
    const bf16_t* __restrict__ A, const bf16_t* __restrict__ Bw, float* __restrict__ C,
    int M, int N, int K, int nby) {
  __shared__ __align__(16) char lds[147456];
  int tid = threadIdx.x;
  int w = tid >> 6, lane = tid & 63;
  int wm = w >> 1, wn = w & 1;
  int mr = lane & 15, kg = lane >> 4;

  int nwg = gridDim.x;
  int orig = blockIdx.x;
  int wgid = (orig & 7) * (nwg >> 3) + (orig >> 3);
  int by = wgid % nby, bx = wgid / nby;
  int row0 = by * 256, col0 = bx * 128;

  size_t aoff[4], boff[2];
#pragma unroll
  for (int it = 0; it < 4; ++it) {
    int c = tid + it * 512;
    int r = c >> 3;
    int chs = (c & 7) ^ (r & 7);
    aoff[it] = (size_t)(row0 + r) * K + chs * 8;
  }
#pragma unroll
  for (int it = 0; it < 2; ++it) {
    int c = tid + it * 512;
    int r = c >> 3;
    int chs = (c & 7) ^ (r & 7);
    boff[it] = (size_t)(col0 + r) * K + chs * 8;
  }

  auto stageA = [&](int buf, int kt, int half) {
    char* Ad = &lds[buf * 49152];
#pragma unroll
    for (int it = half * 2; it < half * 2 + 2; ++it)
      async_copy16(A + aoff[it] + kt * 64, Ad + (tid + it * 512) * 16);
  };
  auto stageB = [&](int buf, int kt) {
    char* Bd = &lds[buf * 49152 + 32768];
#pragma unroll
    for (int it = 0; it < 2; ++it)
      async_copy16(Bw + boff[it] + kt * 64, Bd + (tid + it * 512) * 16);
  };

  f32x4 zero = {0.f, 0.f, 0.f, 0.f};
  f32x4 acc[4][4];
#pragma unroll
  for (int mi = 0; mi < 4; ++mi)
#pragma unroll
    for (int ni = 0; ni < 4; ++ni) acc[mi][ni] = zero;

  int nt = K >> 6;
  stageA(0, 0, 0); stageA(0, 0, 1); stageB(0, 0);
  stageA(1, 1, 0); stageA(1, 1, 1); stageB(1, 1);
  asm volatile("s_waitcnt vmcnt(6)" ::: "memory");
  __builtin_amdgcn_sched_barrier(0);
  __builtin_amdgcn_s_barrier();
  __builtin_amdgcn_sched_barrier(0);

#pragma unroll 1
  for (int t = 0; t < nt; ++t) {
    int cur = t % 3;
    int nxt = (t + 2) % 3;
    int kt2 = (t + 2 < nt) ? (t + 2) : t;
    const char* Ab = &lds[cur * 49152];
    const char* Bb = &lds[cur * 49152 + 32768];
    bf16x8 af[4][2], bfr[4][2];
#pragma unroll
    for (int mi = 0; mi < 4; ++mi) {
      int row = wm * 64 + mi * 16 + mr;
      const char* rb = Ab + row * 128;
      int sz = (row & 7) << 4;
      af[mi][0] = *(const bf16x8*)(rb + ((kg * 16) ^ sz));
      af[mi][1] = *(const bf16x8*)(rb + ((64 + kg * 16) ^ sz));
    }
#pragma unroll
    for (int ni = 0; ni < 4; ++ni) {
      int row = wn * 64 + ni * 16 + mr;
      const char* rb = Bb + row * 128;
      int sz = (row & 7) << 4;
      bfr[ni][0] = *(const bf16x8*)(rb + ((kg * 16) ^ sz));
      bfr[ni][1] = *(const bf16x8*)(rb + ((64 + kg * 16) ^ sz));
    }
    stageA(nxt, kt2, 0);
    __builtin_amdgcn_s_setprio(1);
#pragma unroll
    for (int mi = 0; mi < 4; ++mi) {
      acc[mi][0] = MFMA16(af[mi][0], bfr[0][0], acc[mi][0]);
      acc[mi][0] = MFMA16(af[mi][1], bfr[0][1], acc[mi][0]);
    }
    __builtin_amdgcn_s_setprio(0);
    stageA(nxt, kt2, 1);
    __builtin_amdgcn_s_setprio(1);
#pragma unroll
    for (int mi = 0; mi < 4; ++mi) {
      acc[mi][1] = MFMA16(af[mi][0], bfr[1][0], acc[mi][1]);
      acc[mi][1] = MFMA16(af[mi][1], bfr[1][1], acc[mi][1]);
    }
    __builtin_amdgcn_s_setprio(0);
    stageB(nxt, kt2);
    __builtin_amdgcn_s_setprio(1);
#pragma unroll
    for (int mi = 0; mi < 4; ++mi) {
      acc[mi][2] = MFMA16(af[mi][0], bfr[2][0], acc[mi][2]);
      acc[mi][2] = MFMA16(af[mi][1], bfr[2][1], acc[mi][2]);
      acc[mi][3] = MFMA16(af[mi][0], bfr[3][0], acc[mi][3]);
      acc[mi][3] = MFMA16(af[mi][1], bfr[3][1], acc[mi][3]);
    }
    __builtin_amdgcn_s_setprio(0);
    asm volatile("s_waitcnt vmcnt(6)" ::: "memory");
    __builtin_amdgcn_sched_barrier(0);
    __builtin_amdgcn_s_barrier();
    __builtin_amdgcn_sched_barrier(0);
  }
  asm volatile("s_waitcnt vmcnt(0)" ::: "memory");
  __syncthreads();

#pragma unroll
  for (int mi = 0; mi < 4; ++mi)
#pragma unroll
    for (int ni = 0; ni < 4; ++ni)
#pragma unroll
      for (int jj = 0; jj < 4; ++jj) {
        int row = row0 + wm * 64 + mi * 16 + kg * 4 + jj;
        int col = col0 + wn * 64 + ni * 16 + mr;
        C[(size_t)row * N + col] = acc[mi][ni][jj];
      }
}

// ---------------- causal flash attention (v2, unchanged) ----------------
__global__ __launch_bounds__(256) void attn_kernel(
    const bf16_t* __restrict__ qg, const bf16_t* __restrict__ kgl,
    const bf16_t* __restrict__ vtg, bf16_t* __restrict__ og) {
  __shared__ __align__(16) bf16_t Ks[2][64 * 128];
  __shared__ __align__(16) bf16_t Vs[2][128 * 64];
  __shared__ __align__(16) bf16_t plds[4][1024];
  const int T = 2048;
  int tid = threadIdx.x;
  int w = tid >> 6, lane = tid & 63;
  int mr = lane & 15, kg = lane >> 4;
  int swz = (mr & 7) << 4;

  int L = blockIdx.y * 16 + blockIdx.x;
  int role = (L & 7) * 64 + (L >> 3);
  int bx = role & 15, bh = role >> 4;

  const bf16_t* Q = qg + (size_t)bh * T * 128;
  const bf16_t* K = kgl + (size_t)bh * T * 128;
  const bf16_t* Vt = vtg + (size_t)bh * 128 * T;

  int sb = tid * 16;
  int krl = sb >> 8;
  int kc = (sb & 255) ^ ((krl & 7) << 4);
  size_t ksrc = (size_t)krl * 128 + (kc >> 1);
  int vdl = sb >> 7;
  int vc = (sb & 127) ^ ((vdl & 7) << 4);
  size_t vsrc = (size_t)vdl * 2048 + (vc >> 1);

  auto stage = [&](int buf, int kb) {
#pragma unroll
    for (int it = 0; it < 4; ++it)
      async_copy16(K + (size_t)(kb + it * 16) * 128 + ksrc, &Ks[buf][it * 2048 + tid * 8]);
#pragma unroll
    for (int it = 0; it < 4; ++it)
      async_copy16(Vt + (size_t)it * 65536 + kb + vsrc, &Vs[buf][it * 2048 + tid * 8]);
  };

  const float cscale = 0.12751744f;  // (1/sqrt(128)) * log2(e)
  f32x4 zero = {0.f, 0.f, 0.f, 0.f};
  bf16_t* P = &plds[w][0];
  int b = bh >> 4, h = bh & 15;

#pragma unroll 1
  for (int ph = 0; ph < 2; ++ph) {
    int qb = ph ? bx : (31 - bx);
    int qr0 = qb * 64 + w * 16;
    bf16x8 qf[4];
#pragma unroll
    for (int db = 0; db < 4; ++db)
      qf[db] = *(const bf16x8*)(Q + (size_t)(qr0 + mr) * 128 + db * 32 + kg * 8);

    f32x4 acc[8];
#pragma unroll
    for (int d2 = 0; d2 < 8; ++d2) acc[d2] = zero;
    float mrun[4] = {-1e30f, -1e30f, -1e30f, -1e30f};
    float lrun[4] = {0.f, 0.f, 0.f, 0.f};

    int nj = qb + 1;
    __syncthreads();
    stage(0, 0);
    int cur = 0;
#pragma unroll 1
    for (int j = 0; j < nj; ++j) {
      __syncthreads();
      if (j + 1 < nj) stage(cur ^ 1, (j + 1) * 64);
      const char* KsB = (const char*)&Ks[cur][0];
      const char* VsB = (const char*)&Vs[cur][0];
      int kb = j * 64;
      f32x4 s[4];
#pragma unroll
      for (int ntl = 0; ntl < 4; ++ntl) {
        s[ntl] = zero;
        int rowb = (ntl * 16 + mr) * 256;
#pragma unroll
        for (int db = 0; db < 4; ++db) {
          bf16x8 kf = *(const bf16x8*)(KsB + rowb + ((db * 64 + kg * 16) ^ swz));
          s[ntl] = MFMA16(qf[db], kf, s[ntl]);
        }
      }
      float pvv[4][4];
      float tmax[4] = {-3e38f, -3e38f, -3e38f, -3e38f};
      bool diag = (j == qb);
#pragma unroll
      for (int ntl = 0; ntl < 4; ++ntl)
#pragma unroll
        for (int jj = 0; jj < 4; ++jj) {
          float v = s[ntl][jj] * cscale;
          if (diag && (kb + ntl * 16 + mr) > (qr0 + kg * 4 + jj)) v = -1e30f;
          pvv[ntl][jj] = v;
          tmax[jj] = fmaxf(tmax[jj], v);
        }
#pragma unroll
      for (int m = 1; m < 16; m <<= 1)
#pragma unroll
        for (int jj = 0; jj < 4; ++jj)
          tmax[jj] = fmaxf(tmax[jj], __shfl_xor(tmax[jj], m, 64));
      bool ok = true;
#pragma unroll
      for (int jj = 0; jj < 4; ++jj) ok &= (tmax[jj] <= mrun[jj] + 8.0f);
      if (!__all(ok)) {
#pragma unroll
        for (int jj = 0; jj < 4; ++jj) {
          float mn = fmaxf(mrun[jj], tmax[jj]);
          float corr = __builtin_amdgcn_exp2f(mrun[jj] - mn);
          mrun[jj] = mn;
          lrun[jj] *= corr;
#pragma unroll
          for (int d2 = 0; d2 < 8; ++d2) acc[d2][jj] *= corr;
        }
      }
      float rs[4] = {0.f, 0.f, 0.f, 0.f};
#pragma unroll
      for (int ntl = 0; ntl < 4; ++ntl)
#pragma unroll
        for (int jj = 0; jj < 4; ++jj) {
          float p = __builtin_amdgcn_exp2f(pvv[ntl][jj] - mrun[jj]);
          pvv[ntl][jj] = p;
          rs[jj] += p;
        }
#pragma unroll
      for (int m = 1; m < 16; m <<= 1)
#pragma unroll
        for (int jj = 0; jj < 4; ++jj) rs[jj] += __shfl_xor(rs[jj], m, 64);
#pragma unroll
      for (int jj = 0; jj < 4; ++jj) lrun[jj] += rs[jj];
#pragma unroll
      for (int ntl = 0; ntl < 4; ++ntl)
#pragma unroll
        for (int jj = 0; jj < 4; ++jj) {
          int rr = kg * 4 + jj;
          int cbyte = (mr + ntl * 16) * 2;
          *(bf16_t*)((char*)P + rr * 128 + (cbyte ^ ((rr & 7) << 4))) = (bf16_t)pvv[ntl][jj];
        }
#pragma unroll
      for (int ks = 0; ks < 2; ++ks) {
        int cb = (ks * 32 + kg * 8) * 2;
        bf16x8 pa = *(const bf16x8*)((const char*)P + mr * 128 + (cb ^ ((mr & 7) << 4)));
#pragma unroll
        for (int d2 = 0; d2 < 8; ++d2) {
          bf16x8 vf = *(const bf16x8*)(VsB + (d2 * 16 + mr) * 128 + ((ks * 64 + kg * 16) ^ swz));
          acc[d2] = MFMA16(pa, vf, acc[d2]);
        }
      }
      cur ^= 1;
    }
#pragma unroll
    for (int jj = 0; jj < 4; ++jj) {
      float invl = 1.0f / lrun[jj];
      int t = qr0 + kg * 4 + jj;
      size_t row = (size_t)b * 2048 + h * 128 + (t >> 4);
      bf16_t* orow = og + row * 2048 + (t & 15) * 128;
#pragma unroll
      for (int d2 = 0; d2 < 8; ++d2)
        orow[d2 * 16 + mr] = (bf16_t)(acc[d2][jj] * invl);
    }
  }
}

extern "C" void kernel_launch(void* const* d_in, const int* in_sizes, int n_in,
                              void* d_out, int out_size, void* d_ws, size_t ws_size,
                              hipStream_t stream) {
  const float* x = (const float*)d_in[0];      // [2,2048,2048]
  const float* wqkv = (const float*)d_in[1];   // [6144,2048]
  const float* wproj = (const float*)d_in[2];  // [2048,2048]
  float* out = (float*)d_out;                  // [2,2048,2048]
  char* ws = (char*)d_ws;

  const size_t OFF_WQKV = 16777216;
  const size_t OFF_Q = 41943040;
  const size_t OFF_K = 58720256;
  const size_t OFF_VT = 75497472;

  bf16_t* xb = (bf16_t*)(ws);
  bf16_t* wqkvb = (bf16_t*)(ws + OFF_WQKV);
  bf16_t* g_q = (bf16_t*)(ws + OFF_Q);
  bf16_t* g_k = (bf16_t*)(ws + OFF_K);
  bf16_t* g_vt = (bf16_t*)(ws + OFF_VT);
  bf16_t* g_att = (bf16_t*)(ws);               // alias xb (dead after gemm1)
  bf16_t* wprojb = (bf16_t*)(ws + OFF_WQKV);   // alias wqkvb (dead after gemm1)

  cast_f32_bf16<<<2048, 256, 0, stream>>>(x, xb, 8388608 / 8);
  cast_f32_bf16<<<2048, 256, 0, stream>>>(wqkv, wqkvb, 12582912 / 8);
  // qkv gemm: 256^2 tiles, BK=32, depth-3, fused RoPE/V^T epilogue (384 blocks)
  gemm_qkv<<<384, 512, 0, stream>>>(xb, wqkvb, g_q, g_k, g_vt, 2048);
  cast_f32_bf16<<<2048, 256, 0, stream>>>(wproj, wprojb, 4194304 / 8);
  attn_kernel<<<dim3(16, 32), 256, 0, stream>>>(g_q, g_k, g_vt, g_att);
  // output projection (256x128 tiles, 256 blocks = 1 full CU round)
  gemm256<0><<<256, 512, 0, stream>>>(g_att, wprojb, out, 4096, 2048, 2048, 16);
}

// Round 8
// 276.521 us; speedup vs baseline: 1.0346x; 1.0034x over previous
//
#include <hip/hip_runtime.h>
#include <hip/hip_bf16.h>

typedef __bf16 bf16_t;
typedef __bf16 bf16x8 __attribute__((ext_vector_type(8)));
typedef float f32x4 __attribute__((ext_vector_type(4)));

#define MFMA16(a, b, c) __builtin_amdgcn_mfma_f32_16x16x32_bf16(a, b, c, 0, 0, 0)

__device__ __forceinline__ void async_copy16(const void* g, void* l) {
  __builtin_amdgcn_global_load_lds(
      (const __attribute__((address_space(1))) void*)g,
      (__attribute__((address_space(3))) void*)l, 16, 0, 0);
}

// ---------------- cast f32 -> bf16 (8 elems/thread) ----------------
__global__ void cast_f32_bf16(const float* __restrict__ in, bf16_t* __restrict__ out, int n8) {
  int stride = gridDim.x * blockDim.x;
  for (int i = blockIdx.x * blockDim.x + threadIdx.x; i < n8; i += stride) {
    const float* p = in + (size_t)i * 8;
    f32x4 a = *(const f32x4*)p;
    f32x4 b = *(const f32x4*)(p + 4);
    bf16x8 o;
    o[0] = (bf16_t)a[0]; o[1] = (bf16_t)a[1]; o[2] = (bf16_t)a[2]; o[3] = (bf16_t)a[3];
    o[4] = (bf16_t)b[0]; o[5] = (bf16_t)b[1]; o[6] = (bf16_t)b[2]; o[7] = (bf16_t)b[3];
    *(bf16x8*)(out + (size_t)i * 8) = o;
  }
}

// ======== GEMM1 (QKV): 256x256, BK=64, 512thr (8 waves 2Mx4N), 4-phase/K-tile ========
// Phase-split schedule (T3+T4): per phase {ds_read frag group | 2 stage instrs |
// counted vmcnt {4,5,6,3} | barrier | lgkm0 | 16 MFMA | barrier}. Never drains.
// Stage units need-aligned: B0,B1 | B2,B3 | A0,A1 | A2,A3 (permuted row coverage).
__global__ __launch_bounds__(512, 2) void gemm_qkv(
    const bf16_t* __restrict__ A, const bf16_t* __restrict__ Bw,
    bf16_t* __restrict__ qo, bf16_t* __restrict__ ko, bf16_t* __restrict__ vto,
    int K) {
  // buf q at q*65536: A 32KB (rows permuted by unit), B 32KB @ +32768
  __shared__ __align__(16) char lds[131072];
  int tid = threadIdx.x;
  int w = tid >> 6, lane = tid & 63;
  int wm = w & 1, wn = w >> 1;
  int mr = lane & 15, kg = lane >> 4;

  // XCD chunking (R7 proven): chunk rect 4(by) x 12(bx), FETCH 82MB
  int orig = blockIdx.x;
  int chunk = orig & 7, i = orig >> 3;
  int by = (chunk & 3) * 4 + (i & 3);
  int bx = (chunk >> 2) * 12 + (i >> 2);
  int row0 = by * 256, col0 = bx * 256;

  // stage source offsets (inverse-swizzled global, linear LDS dest)
  int lr = tid >> 3, ch = (tid & 7) ^ (lr & 7);
  size_t aoff[4], boff[4];
#pragma unroll
  for (int g = 0; g < 4; ++g) {
    int gr = g * 32 + (lr & 31) + (lr >> 5) * 128;   // rows {g*32..+31} U {128+g*32..+31}
    aoff[g] = (size_t)(row0 + gr) * K + ch * 8;
  }
#pragma unroll
  for (int p = 0; p < 4; ++p) {
    int gr = (lr >> 4) * 64 + p * 16 + (lr & 15);    // rows {p*16+64k..+15}
    boff[p] = (size_t)(col0 + gr) * K + ch * 8;
  }

  auto stgA = [&](int q, int g, int kt) {
    async_copy16(A + aoff[g] + kt * 64, lds + q * 65536 + g * 8192 + tid * 16);
  };
  auto stgB = [&](int q, int p, int kt) {
    async_copy16(Bw + boff[p] + kt * 64, lds + q * 65536 + 32768 + p * 8192 + tid * 16);
  };

  f32x4 zero = {0.f, 0.f, 0.f, 0.f};
  f32x4 acc[8][4];
#pragma unroll
  for (int mi = 0; mi < 8; ++mi)
#pragma unroll
    for (int ni = 0; ni < 4; ++ni) acc[mi][ni] = zero;

  // B ds_read rows (physical = logical unit layout): rowB(ni) = ni*64 + wn*16 + mr
  // A ds_read rows: rowA(mi) = (mi>>1)*64 + wm*32 + (mi&1)*16 + mr
  int nt = K >> 6;  // 32

  // prologue: tile 0, order B0..B3, A0..A3; one-time drain
  stgB(0, 0, 0); stgB(0, 1, 0); stgB(0, 2, 0); stgB(0, 3, 0);
  stgA(0, 0, 0); stgA(0, 1, 0); stgA(0, 2, 0); stgA(0, 3, 0);
  asm volatile("s_waitcnt vmcnt(0)" ::: "memory");
  __builtin_amdgcn_sched_barrier(0);
  __builtin_amdgcn_s_barrier();
  __builtin_amdgcn_sched_barrier(0);

#pragma unroll 1
  for (int t = 0; t < nt; ++t) {
    int q = t & 1, qn = q ^ 1;
    int kt = (t + 1 < nt) ? (t + 1) : t;  // tail: dummy restage (never read, drained)
    const char* Ab = lds + q * 65536;
    const char* Bb = Ab + 32768;
    bf16x8 bf[4][2];

#define QKV_PHASE(MI0, STG0, STG1, WAIT)                                        \
    {                                                                           \
      int r0 = ((MI0) >> 1) * 64 + wm * 32 + mr;                                \
      int r1 = r0 + 16;                                                         \
      bf16x8 a00 = *(const bf16x8*)(Ab + r0 * 128 + ((kg * 16) ^ ((r0 & 7) << 4)));      \
      bf16x8 a01 = *(const bf16x8*)(Ab + r0 * 128 + ((64 + kg * 16) ^ ((r0 & 7) << 4))); \
      bf16x8 a10 = *(const bf16x8*)(Ab + r1 * 128 + ((kg * 16) ^ ((r1 & 7) << 4)));      \
      bf16x8 a11 = *(const bf16x8*)(Ab + r1 * 128 + ((64 + kg * 16) ^ ((r1 & 7) << 4))); \
      STG0; STG1;                                                               \
      __builtin_amdgcn_sched_barrier(0);                                        \
      asm volatile("s_waitcnt vmcnt(" #WAIT ")" ::: "memory");                  \
      __builtin_amdgcn_s_barrier();                                             \
      asm volatile("s_waitcnt lgkmcnt(0)" ::: "memory");                        \
      __builtin_amdgcn_sched_barrier(0);                                        \
      __builtin_amdgcn_s_setprio(1);                                            \
      _Pragma("unroll")                                                         \
      for (int ni = 0; ni < 4; ++ni) {                                          \
        acc[MI0][ni] = MFMA16(a00, bf[ni][0], acc[MI0][ni]);                    \
        acc[MI0][ni] = MFMA16(a01, bf[ni][1], acc[MI0][ni]);                    \
        acc[(MI0) + 1][ni] = MFMA16(a10, bf[ni][0], acc[(MI0) + 1][ni]);        \
        acc[(MI0) + 1][ni] = MFMA16(a11, bf[ni][1], acc[(MI0) + 1][ni]);        \
      }                                                                         \
      __builtin_amdgcn_s_setprio(0);                                            \
      __builtin_amdgcn_sched_barrier(0);                                        \
      __builtin_amdgcn_s_barrier();                                             \
      __builtin_amdgcn_sched_barrier(0);                                        \
    }

    // ---- phase 0: B-all + A-group0 reads; stage B0,B1(t+1); vmcnt(4) ----
#pragma unroll
    for (int ni = 0; ni < 4; ++ni) {
      int rb = ni * 64 + wn * 16 + mr;
      bf[ni][0] = *(const bf16x8*)(Bb + rb * 128 + ((kg * 16) ^ ((rb & 7) << 4)));
      bf[ni][1] = *(const bf16x8*)(Bb + rb * 128 + ((64 + kg * 16) ^ ((rb & 7) << 4)));
    }
    QKV_PHASE(0, stgB(qn, 0, kt), stgB(qn, 1, kt), 4)
    // ---- phase 1: A-group1; stage B2,B3; vmcnt(5) ----
    QKV_PHASE(2, stgB(qn, 2, kt), stgB(qn, 3, kt), 5)
    // ---- phase 2: A-group2; stage A0,A1; vmcnt(6) ----
    QKV_PHASE(4, stgA(qn, 0, kt), stgA(qn, 1, kt), 6)
    // ---- phase 3: A-group3; stage A2,A3; vmcnt(3) confirms next tile's B-all+A0 ----
    QKV_PHASE(6, stgA(qn, 2, kt), stgA(qn, 3, kt), 3)
#undef QKV_PHASE
  }
  asm volatile("s_waitcnt vmcnt(0)" ::: "memory");
  __syncthreads();

  // ---- fused epilogue via LDS roundtrip (R7 proven, verbatim) ----
  char* tb = &lds[0];
  int s = col0 >> 11;               // 0:q 1:k 2:v
  int h0 = (col0 >> 7) & 15;
  int b = row0 >> 11, t0 = row0 & 2047;
  if (s < 2) {
#pragma unroll
    for (int mi = 0; mi < 8; ++mi)
#pragma unroll
      for (int ni = 0; ni < 4; ++ni)
#pragma unroll
        for (int jj = 0; jj < 4; ++jj) {
          int rl = wm * 128 + mi * 16 + kg * 4 + jj;
          int cb = (wn * 64 + ni * 16 + mr) * 2;
          *(bf16_t*)(tb + rl * 512 + (cb ^ ((rl & 7) << 4))) = (bf16_t)acc[mi][ni][jj];
        }
    __syncthreads();
    int r = tid >> 1, hs = tid & 1;
    const char* rowb = tb + r * 512;
    int sz = (r & 7) << 4;
    int t = t0 + r;
    bf16_t* dst = (s == 0 ? qo : ko) + ((size_t)((b * 16 + h0 + hs) * 2048 + t)) * 128;
    float tf = (float)t;
    const float cinv = -0.20762050593046014f;  // -log2(10000)/64
    bf16x8 vin[16];
#pragma unroll
    for (int m = 0; m < 16; ++m)
      vin[m] = *(const bf16x8*)(rowb + ((hs * 256 + m * 16) ^ sz));
#pragma unroll
    for (int m = 0; m < 8; ++m) {
      bf16x8 o1, o2;
#pragma unroll
      for (int e = 0; e < 8; ++e) {
        float ang = tf * exp2f((float)(m * 8 + e) * cinv);
        float sv = __sinf(ang), cv = __cosf(ang);
        float x1 = (float)vin[m][e], x2 = (float)vin[m + 8][e];
        o1[e] = (bf16_t)(x1 * cv - x2 * sv);
        o2[e] = (bf16_t)(x2 * cv + x1 * sv);
      }
      *(bf16x8*)(dst + m * 8) = o1;
      *(bf16x8*)(dst + 64 + m * 8) = o2;
    }
  } else {
#pragma unroll
    for (int mi = 0; mi < 8; ++mi)
#pragma unroll
      for (int ni = 0; ni < 4; ++ni)
#pragma unroll
        for (int jj = 0; jj < 4; ++jj) {
          int rl = wm * 128 + mi * 16 + kg * 4 + jj;
          int cl = wn * 64 + ni * 16 + mr;
          *(bf16_t*)(tb + cl * 512 + ((rl * 2) ^ ((cl & 7) << 4))) = (bf16_t)acc[mi][ni][jj];
        }
    __syncthreads();
    int d = tid >> 1, ts = tid & 1;
    const char* rowb = tb + d * 512;
    int sz = (d & 7) << 4;
    bf16_t* dst = vto + ((size_t)((b * 16 + h0 + (d >> 7)) * 128 + (d & 127))) * 2048 +
                  t0 + ts * 128;
#pragma unroll
    for (int m = 0; m < 16; ++m)
      *(bf16x8*)(dst + m * 8) = *(const bf16x8*)(rowb + ((ts * 256 + m * 16) ^ sz));
  }
}

// ------- GEMM2: 256x128 tile, BK=64, 512 thr, depth-2 (R6 proven, verbatim) -------
__global__ __launch_bounds__(512, 2) void gemm256(
    const bf16_t* __restrict__ A, const bf16_t* __restrict__ Bw, float* __restrict__ C,
    int M, int N, int K, int nby) {
  __shared__ __align__(16) char lds[147456];
  int tid = threadIdx.x;
  int w = tid >> 6, lane = tid & 63;
  int wm = w >> 1, wn = w & 1;
  int mr = lane & 15, kg = lane >> 4;

  int nwg = gridDim.x;
  int orig = blockIdx.x;
  int wgid = (orig & 7) * (nwg >> 3) + (orig >> 3);
  int by = wgid % nby, bx = wgid / nby;
  int row0 = by * 256, col0 = bx * 128;

  size_t aoff[4], boff[2];
#pragma unroll
  for (int it = 0; it < 4; ++it) {
    int c = tid + it * 512;
    int r = c >> 3;
    int chs = (c & 7) ^ (r & 7);
    aoff[it] = (size_t)(row0 + r) * K + chs * 8;
  }
#pragma unroll
  for (int it = 0; it < 2; ++it) {
    int c = tid + it * 512;
    int r = c >> 3;
    int chs = (c & 7) ^ (r & 7);
    boff[it] = (size_t)(col0 + r) * K + chs * 8;
  }

  auto stageA = [&](int buf, int kt, int half) {
    char* Ad = &lds[buf * 49152];
#pragma unroll
    for (int it = half * 2; it < half * 2 + 2; ++it)
      async_copy16(A + aoff[it] + kt * 64, Ad + (tid + it * 512) * 16);
  };
  auto stageB = [&](int buf, int kt) {
    char* Bd = &lds[buf * 49152 + 32768];
#pragma unroll
    for (int it = 0; it < 2; ++it)
      async_copy16(Bw + boff[it] + kt * 64, Bd + (tid + it * 512) * 16);
  };

  f32x4 zero = {0.f, 0.f, 0.f, 0.f};
  f32x4 acc[4][4];
#pragma unroll
  for (int mi = 0; mi < 4; ++mi)
#pragma unroll
    for (int ni = 0; ni < 4; ++ni) acc[mi][ni] = zero;

  int nt = K >> 6;
  stageA(0, 0, 0); stageA(0, 0, 1); stageB(0, 0);
  stageA(1, 1, 0); stageA(1, 1, 1); stageB(1, 1);
  asm volatile("s_waitcnt vmcnt(6)" ::: "memory");
  __builtin_amdgcn_sched_barrier(0);
  __builtin_amdgcn_s_barrier();
  __builtin_amdgcn_sched_barrier(0);

#pragma unroll 1
  for (int t = 0; t < nt; ++t) {
    int cur = t % 3;
    int nxt = (t + 2) % 3;
    int kt2 = (t + 2 < nt) ? (t + 2) : t;
    const char* Ab = &lds[cur * 49152];
    const char* Bb = &lds[cur * 49152 + 32768];
    bf16x8 af[4][2], bfr[4][2];
#pragma unroll
    for (int mi = 0; mi < 4; ++mi) {
      int row = wm * 64 + mi * 16 + mr;
      const char* rb = Ab + row * 128;
      int sz = (row & 7) << 4;
      af[mi][0] = *(const bf16x8*)(rb + ((kg * 16) ^ sz));
      af[mi][1] = *(const bf16x8*)(rb + ((64 + kg * 16) ^ sz));
    }
#pragma unroll
    for (int ni = 0; ni < 4; ++ni) {
      int row = wn * 64 + ni * 16 + mr;
      const char* rb = Bb + row * 128;
      int sz = (row & 7) << 4;
      bfr[ni][0] = *(const bf16x8*)(rb + ((kg * 16) ^ sz));
      bfr[ni][1] = *(const bf16x8*)(rb + ((64 + kg * 16) ^ sz));
    }
    stageA(nxt, kt2, 0);
    __builtin_amdgcn_s_setprio(1);
#pragma unroll
    for (int mi = 0; mi < 4; ++mi) {
      acc[mi][0] = MFMA16(af[mi][0], bfr[0][0], acc[mi][0]);
      acc[mi][0] = MFMA16(af[mi][1], bfr[0][1], acc[mi][0]);
    }
    __builtin_amdgcn_s_setprio(0);
    stageA(nxt, kt2, 1);
    __builtin_amdgcn_s_setprio(1);
#pragma unroll
    for (int mi = 0; mi < 4; ++mi) {
      acc[mi][1] = MFMA16(af[mi][0], bfr[1][0], acc[mi][1]);
      acc[mi][1] = MFMA16(af[mi][1], bfr[1][1], acc[mi][1]);
    }
    __builtin_amdgcn_s_setprio(0);
    stageB(nxt, kt2);
    __builtin_amdgcn_s_setprio(1);
#pragma unroll
    for (int mi = 0; mi < 4; ++mi) {
      acc[mi][2] = MFMA16(af[mi][0], bfr[2][0], acc[mi][2]);
      acc[mi][2] = MFMA16(af[mi][1], bfr[2][1], acc[mi][2]);
      acc[mi][3] = MFMA16(af[mi][0], bfr[3][0], acc[mi][3]);
      acc[mi][3] = MFMA16(af[mi][1], bfr[3][1], acc[mi][3]);
    }
    __builtin_amdgcn_s_setprio(0);
    asm volatile("s_waitcnt vmcnt(6)" ::: "memory");
    __builtin_amdgcn_sched_barrier(0);
    __builtin_amdgcn_s_barrier();
    __builtin_amdgcn_sched_barrier(0);
  }
  asm volatile("s_waitcnt vmcnt(0)" ::: "memory");
  __syncthreads();

#pragma unroll
  for (int mi = 0; mi < 4; ++mi)
#pragma unroll
    for (int ni = 0; ni < 4; ++ni)
#pragma unroll
      for (int jj = 0; jj < 4; ++jj) {
        int row = row0 + wm * 64 + mi * 16 + kg * 4 + jj;
        int col = col0 + wn * 64 + ni * 16 + mr;
        C[(size_t)row * N + col] = acc[mi][ni][jj];
      }
}

// ---------------- causal flash attention (v2, unchanged) ----------------
__global__ __launch_bounds__(256) void attn_kernel(
    const bf16_t* __restrict__ qg, const bf16_t* __restrict__ kgl,
    const bf16_t* __restrict__ vtg, bf16_t* __restrict__ og) {
  __shared__ __align__(16) bf16_t Ks[2][64 * 128];
  __shared__ __align__(16) bf16_t Vs[2][128 * 64];
  __shared__ __align__(16) bf16_t plds[4][1024];
  const int T = 2048;
  int tid = threadIdx.x;
  int w = tid >> 6, lane = tid & 63;
  int mr = lane & 15, kg = lane >> 4;
  int swz = (mr & 7) << 4;

  int L = blockIdx.y * 16 + blockIdx.x;
  int role = (L & 7) * 64 + (L >> 3);
  int bx = role & 15, bh = role >> 4;

  const bf16_t* Q = qg + (size_t)bh * T * 128;
  const bf16_t* K = kgl + (size_t)bh * T * 128;
  const bf16_t* Vt = vtg + (size_t)bh * 128 * T;

  int sb = tid * 16;
  int krl = sb >> 8;
  int kc = (sb & 255) ^ ((krl & 7) << 4);
  size_t ksrc = (size_t)krl * 128 + (kc >> 1);
  int vdl = sb >> 7;
  int vc = (sb & 127) ^ ((vdl & 7) << 4);
  size_t vsrc = (size_t)vdl * 2048 + (vc >> 1);

  auto stage = [&](int buf, int kb) {
#pragma unroll
    for (int it = 0; it < 4; ++it)
      async_copy16(K + (size_t)(kb + it * 16) * 128 + ksrc, &Ks[buf][it * 2048 + tid * 8]);
#pragma unroll
    for (int it = 0; it < 4; ++it)
      async_copy16(Vt + (size_t)it * 65536 + kb + vsrc, &Vs[buf][it * 2048 + tid * 8]);
  };

  const float cscale = 0.12751744f;  // (1/sqrt(128)) * log2(e)
  f32x4 zero = {0.f, 0.f, 0.f, 0.f};
  bf16_t* P = &plds[w][0];
  int b = bh >> 4, h = bh & 15;

#pragma unroll 1
  for (int ph = 0; ph < 2; ++ph) {
    int qb = ph ? bx : (31 - bx);
    int qr0 = qb * 64 + w * 16;
    bf16x8 qf[4];
#pragma unroll
    for (int db = 0; db < 4; ++db)
      qf[db] = *(const bf16x8*)(Q + (size_t)(qr0 + mr) * 128 + db * 32 + kg * 8);

    f32x4 acc[8];
#pragma unroll
    for (int d2 = 0; d2 < 8; ++d2) acc[d2] = zero;
    float mrun[4] = {-1e30f, -1e30f, -1e30f, -1e30f};
    float lrun[4] = {0.f, 0.f, 0.f, 0.f};

    int nj = qb + 1;
    __syncthreads();
    stage(0, 0);
    int cur = 0;
#pragma unroll 1
    for (int j = 0; j < nj; ++j) {
      __syncthreads();
      if (j + 1 < nj) stage(cur ^ 1, (j + 1) * 64);
      const char* KsB = (const char*)&Ks[cur][0];
      const char* VsB = (const char*)&Vs[cur][0];
      int kb = j * 64;
      f32x4 s[4];
#pragma unroll
      for (int ntl = 0; ntl < 4; ++ntl) {
        s[ntl] = zero;
        int rowb = (ntl * 16 + mr) * 256;
#pragma unroll
        for (int db = 0; db < 4; ++db) {
          bf16x8 kf = *(const bf16x8*)(KsB + rowb + ((db * 64 + kg * 16) ^ swz));
          s[ntl] = MFMA16(qf[db], kf, s[ntl]);
        }
      }
      float pvv[4][4];
      float tmax[4] = {-3e38f, -3e38f, -3e38f, -3e38f};
      bool diag = (j == qb);
#pragma unroll
      for (int ntl = 0; ntl < 4; ++ntl)
#pragma unroll
        for (int jj = 0; jj < 4; ++jj) {
          float v = s[ntl][jj] * cscale;
          if (diag && (kb + ntl * 16 + mr) > (qr0 + kg * 4 + jj)) v = -1e30f;
          pvv[ntl][jj] = v;
          tmax[jj] = fmaxf(tmax[jj], v);
        }
#pragma unroll
      for (int m = 1; m < 16; m <<= 1)
#pragma unroll
        for (int jj = 0; jj < 4; ++jj)
          tmax[jj] = fmaxf(tmax[jj], __shfl_xor(tmax[jj], m, 64));
      bool ok = true;
#pragma unroll
      for (int jj = 0; jj < 4; ++jj) ok &= (tmax[jj] <= mrun[jj] + 8.0f);
      if (!__all(ok)) {
#pragma unroll
        for (int jj = 0; jj < 4; ++jj) {
          float mn = fmaxf(mrun[jj], tmax[jj]);
          float corr = __builtin_amdgcn_exp2f(mrun[jj] - mn);
          mrun[jj] = mn;
          lrun[jj] *= corr;
#pragma unroll
          for (int d2 = 0; d2 < 8; ++d2) acc[d2][jj] *= corr;
        }
      }
      float rs[4] = {0.f, 0.f, 0.f, 0.f};
#pragma unroll
      for (int ntl = 0; ntl < 4; ++ntl)
#pragma unroll
        for (int jj = 0; jj < 4; ++jj) {
          float p = __builtin_amdgcn_exp2f(pvv[ntl][jj] - mrun[jj]);
          pvv[ntl][jj] = p;
          rs[jj] += p;
        }
#pragma unroll
      for (int m = 1; m < 16; m <<= 1)
#pragma unroll
        for (int jj = 0; jj < 4; ++jj) rs[jj] += __shfl_xor(rs[jj], m, 64);
#pragma unroll
      for (int jj = 0; jj < 4; ++jj) lrun[jj] += rs[jj];
#pragma unroll
      for (int ntl = 0; ntl < 4; ++ntl)
#pragma unroll
        for (int jj = 0; jj < 4; ++jj) {
          int rr = kg * 4 + jj;
          int cbyte = (mr + ntl * 16) * 2;
          *(bf16_t*)((char*)P + rr * 128 + (cbyte ^ ((rr & 7) << 4))) = (bf16_t)pvv[ntl][jj];
        }
#pragma unroll
      for (int ks = 0; ks < 2; ++ks) {
        int cb = (ks * 32 + kg * 8) * 2;
        bf16x8 pa = *(const bf16x8*)((const char*)P + mr * 128 + (cb ^ ((mr & 7) << 4)));
#pragma unroll
        for (int d2 = 0; d2 < 8; ++d2) {
          bf16x8 vf = *(const bf16x8*)(VsB + (d2 * 16 + mr) * 128 + ((ks * 64 + kg * 16) ^ swz));
          acc[d2] = MFMA16(pa, vf, acc[d2]);
        }
      }
      cur ^= 1;
    }
#pragma unroll
    for (int jj = 0; jj < 4; ++jj) {
      float invl = 1.0f / lrun[jj];
      int t = qr0 + kg * 4 + jj;
      size_t row = (size_t)b * 2048 + h * 128 + (t >> 4);
      bf16_t* orow = og + row * 2048 + (t & 15) * 128;
#pragma unroll
      for (int d2 = 0; d2 < 8; ++d2)
        orow[d2 * 16 + mr] = (bf16_t)(acc[d2][jj] * invl);
    }
  }
}

extern "C" void kernel_launch(void* const* d_in, const int* in_sizes, int n_in,
                              void* d_out, int out_size, void* d_ws, size_t ws_size,
                              hipStream_t stream) {
  const float* x = (const float*)d_in[0];      // [2,2048,2048]
  const float* wqkv = (const float*)d_in[1];   // [6144,2048]
  const float* wproj = (const float*)d_in[2];  // [2048,2048]
  float* out = (float*)d_out;                  // [2,2048,2048]
  char* ws = (char*)d_ws;

  const size_t OFF_WQKV = 16777216;
  const size_t OFF_Q = 41943040;
  const size_t OFF_K = 58720256;
  const size_t OFF_VT = 75497472;

  bf16_t* xb = (bf16_t*)(ws);
  bf16_t* wqkvb = (bf16_t*)(ws + OFF_WQKV);
  bf16_t* g_q = (bf16_t*)(ws + OFF_Q);
  bf16_t* g_k = (bf16_t*)(ws + OFF_K);
  bf16_t* g_vt = (bf16_t*)(ws + OFF_VT);
  bf16_t* g_att = (bf16_t*)(ws);               // alias xb (dead after gemm1)
  bf16_t* wprojb = (bf16_t*)(ws + OFF_WQKV);   // alias wqkvb (dead after gemm1)

  cast_f32_bf16<<<2048, 256, 0, stream>>>(x, xb, 8388608 / 8);
  cast_f32_bf16<<<2048, 256, 0, stream>>>(wqkv, wqkvb, 12582912 / 8);
  // qkv gemm: 256^2 tiles, 4-phase schedule, fused RoPE/V^T epilogue (384 blocks)
  gemm_qkv<<<384, 512, 0, stream>>>(xb, wqkvb, g_q, g_k, g_vt, 2048);
  cast_f32_bf16<<<2048, 256, 0, stream>>>(wproj, wprojb, 4194304 / 8);
  attn_kernel<<<dim3(16, 32), 256, 0, stream>>>(g_q, g_k, g_vt, g_att);
  // output projection (256x128 tiles, 256 blocks = 1 full CU round)
  gemm256<<<256, 512, 0, stream>>>(g_att, wprojb, out, 4096, 2048, 2048, 16);
}

// Round 9
// 267.136 us; speedup vs baseline: 1.0709x; 1.0351x over previous
//
#include <hip/hip_runtime.h>
#include <hip/hip_bf16.h>

typedef __bf16 bf16_t;
typedef __bf16 bf16x8 __attribute__((ext_vector_type(8)));
typedef float f32x4 __attribute__((ext_vector_type(4)));

#define MFMA16(a, b, c) __builtin_amdgcn_mfma_f32_16x16x32_bf16(a, b, c, 0, 0, 0)

__device__ __forceinline__ void async_copy16(const void* g, void* l) {
  __builtin_amdgcn_global_load_lds(
      (const __attribute__((address_space(1))) void*)g,
      (__attribute__((address_space(3))) void*)l, 16, 0, 0);
}

// ---------------- cast f32 -> bf16 (8 elems/thread) ----------------
__global__ void cast_f32_bf16(const float* __restrict__ in, bf16_t* __restrict__ out, int n8) {
  int stride = gridDim.x * blockDim.x;
  for (int i = blockIdx.x * blockDim.x + threadIdx.x; i < n8; i += stride) {
    const float* p = in + (size_t)i * 8;
    f32x4 a = *(const f32x4*)p;
    f32x4 b = *(const f32x4*)(p + 4);
    bf16x8 o;
    o[0] = (bf16_t)a[0]; o[1] = (bf16_t)a[1]; o[2] = (bf16_t)a[2]; o[3] = (bf16_t)a[3];
    o[4] = (bf16_t)b[0]; o[5] = (bf16_t)b[1]; o[6] = (bf16_t)b[2]; o[7] = (bf16_t)b[3];
    *(bf16x8*)(out + (size_t)i * 8) = o;
  }
}

// ======== GEMM-QK: 256x256, BK=64, 512thr (8 waves 2Mx4N), 4-phase (R8 body) ========
// Covers N-cols 0..4095 (q,k) ONLY: grid 16x16 = 256 blocks = ONE full CU round.
// XCD chunks 4(by) x 8(bx).
__global__ __launch_bounds__(512, 2) void gemm_qkv(
    const bf16_t* __restrict__ A, const bf16_t* __restrict__ Bw,
    bf16_t* __restrict__ qo, bf16_t* __restrict__ ko,
    int K) {
  __shared__ __align__(16) char lds[131072];
  int tid = threadIdx.x;
  int w = tid >> 6, lane = tid & 63;
  int wm = w & 1, wn = w >> 1;
  int mr = lane & 15, kg = lane >> 4;

  // XCD chunking: 8 rects of 4(by) x 8(bx)
  int orig = blockIdx.x;
  int chunk = orig & 7, i = orig >> 3;
  int by = (chunk & 3) * 4 + (i & 3);
  int bx = (chunk >> 2) * 8 + (i >> 2);
  int row0 = by * 256, col0 = bx * 256;

  int lr = tid >> 3, ch = (tid & 7) ^ (lr & 7);
  size_t aoff[4], boff[4];
#pragma unroll
  for (int g = 0; g < 4; ++g) {
    int gr = g * 32 + (lr & 31) + (lr >> 5) * 128;
    aoff[g] = (size_t)(row0 + gr) * K + ch * 8;
  }
#pragma unroll
  for (int p = 0; p < 4; ++p) {
    int gr = (lr >> 4) * 64 + p * 16 + (lr & 15);
    boff[p] = (size_t)(col0 + gr) * K + ch * 8;
  }

  auto stgA = [&](int q, int g, int kt) {
    async_copy16(A + aoff[g] + kt * 64, lds + q * 65536 + g * 8192 + tid * 16);
  };
  auto stgB = [&](int q, int p, int kt) {
    async_copy16(Bw + boff[p] + kt * 64, lds + q * 65536 + 32768 + p * 8192 + tid * 16);
  };

  f32x4 zero = {0.f, 0.f, 0.f, 0.f};
  f32x4 acc[8][4];
#pragma unroll
  for (int mi = 0; mi < 8; ++mi)
#pragma unroll
    for (int ni = 0; ni < 4; ++ni) acc[mi][ni] = zero;

  int nt = K >> 6;  // 32

  stgB(0, 0, 0); stgB(0, 1, 0); stgB(0, 2, 0); stgB(0, 3, 0);
  stgA(0, 0, 0); stgA(0, 1, 0); stgA(0, 2, 0); stgA(0, 3, 0);
  asm volatile("s_waitcnt vmcnt(0)" ::: "memory");
  __builtin_amdgcn_sched_barrier(0);
  __builtin_amdgcn_s_barrier();
  __builtin_amdgcn_sched_barrier(0);

#pragma unroll 1
  for (int t = 0; t < nt; ++t) {
    int q = t & 1, qn = q ^ 1;
    int kt = (t + 1 < nt) ? (t + 1) : t;
    const char* Ab = lds + q * 65536;
    const char* Bb = Ab + 32768;
    bf16x8 bf[4][2];

#define QKV_PHASE(MI0, STG0, STG1, WAIT)                                        \
    {                                                                           \
      int r0 = ((MI0) >> 1) * 64 + wm * 32 + mr;                                \
      int r1 = r0 + 16;                                                         \
      bf16x8 a00 = *(const bf16x8*)(Ab + r0 * 128 + ((kg * 16) ^ ((r0 & 7) << 4)));      \
      bf16x8 a01 = *(const bf16x8*)(Ab + r0 * 128 + ((64 + kg * 16) ^ ((r0 & 7) << 4))); \
      bf16x8 a10 = *(const bf16x8*)(Ab + r1 * 128 + ((kg * 16) ^ ((r1 & 7) << 4)));      \
      bf16x8 a11 = *(const bf16x8*)(Ab + r1 * 128 + ((64 + kg * 16) ^ ((r1 & 7) << 4))); \
      STG0; STG1;                                                               \
      __builtin_amdgcn_sched_barrier(0);                                        \
      asm volatile("s_waitcnt vmcnt(" #WAIT ")" ::: "memory");                  \
      __builtin_amdgcn_s_barrier();                                             \
      asm volatile("s_waitcnt lgkmcnt(0)" ::: "memory");                        \
      __builtin_amdgcn_sched_barrier(0);                                        \
      __builtin_amdgcn_s_setprio(1);                                            \
      _Pragma("unroll")                                                         \
      for (int ni = 0; ni < 4; ++ni) {                                          \
        acc[MI0][ni] = MFMA16(a00, bf[ni][0], acc[MI0][ni]);                    \
        acc[MI0][ni] = MFMA16(a01, bf[ni][1], acc[MI0][ni]);                    \
        acc[(MI0) + 1][ni] = MFMA16(a10, bf[ni][0], acc[(MI0) + 1][ni]);        \
        acc[(MI0) + 1][ni] = MFMA16(a11, bf[ni][1], acc[(MI0) + 1][ni]);        \
      }                                                                         \
      __builtin_amdgcn_s_setprio(0);                                            \
      __builtin_amdgcn_sched_barrier(0);                                        \
      __builtin_amdgcn_s_barrier();                                             \
      __builtin_amdgcn_sched_barrier(0);                                        \
    }

#pragma unroll
    for (int ni = 0; ni < 4; ++ni) {
      int rb = ni * 64 + wn * 16 + mr;
      bf[ni][0] = *(const bf16x8*)(Bb + rb * 128 + ((kg * 16) ^ ((rb & 7) << 4)));
      bf[ni][1] = *(const bf16x8*)(Bb + rb * 128 + ((64 + kg * 16) ^ ((rb & 7) << 4)));
    }
    QKV_PHASE(0, stgB(qn, 0, kt), stgB(qn, 1, kt), 4)
    QKV_PHASE(2, stgB(qn, 2, kt), stgB(qn, 3, kt), 5)
    QKV_PHASE(4, stgA(qn, 0, kt), stgA(qn, 1, kt), 6)
    QKV_PHASE(6, stgA(qn, 2, kt), stgA(qn, 3, kt), 3)
#undef QKV_PHASE
  }
  asm volatile("s_waitcnt vmcnt(0)" ::: "memory");
  __syncthreads();

  // ---- fused RoPE epilogue (q/k only; col0 < 4096 by construction) ----
  char* tb = &lds[0];
  int s = col0 >> 11;
  int h0 = (col0 >> 7) & 15;
  int b = row0 >> 11, t0 = row0 & 2047;
#pragma unroll
  for (int mi = 0; mi < 8; ++mi)
#pragma unroll
    for (int ni = 0; ni < 4; ++ni)
#pragma unroll
      for (int jj = 0; jj < 4; ++jj) {
        int rl = wm * 128 + mi * 16 + kg * 4 + jj;
        int cb = (wn * 64 + ni * 16 + mr) * 2;
        *(bf16_t*)(tb + rl * 512 + (cb ^ ((rl & 7) << 4))) = (bf16_t)acc[mi][ni][jj];
      }
  __syncthreads();
  int r = tid >> 1, hs = tid & 1;
  const char* rowb = tb + r * 512;
  int sz = (r & 7) << 4;
  int t = t0 + r;
  bf16_t* dst = (s == 0 ? qo : ko) + ((size_t)((b * 16 + h0 + hs) * 2048 + t)) * 128;
  float tf = (float)t;
  const float cinv = -0.20762050593046014f;  // -log2(10000)/64
  bf16x8 vin[16];
#pragma unroll
  for (int m = 0; m < 16; ++m)
    vin[m] = *(const bf16x8*)(rowb + ((hs * 256 + m * 16) ^ sz));
#pragma unroll
  for (int m = 0; m < 8; ++m) {
    bf16x8 o1, o2;
#pragma unroll
    for (int e = 0; e < 8; ++e) {
      float ang = tf * exp2f((float)(m * 8 + e) * cinv);
      float sv = __sinf(ang), cv = __cosf(ang);
      float x1 = (float)vin[m][e], x2 = (float)vin[m + 8][e];
      o1[e] = (bf16_t)(x1 * cv - x2 * sv);
      o2[e] = (bf16_t)(x2 * cv + x1 * sv);
    }
    *(bf16x8*)(dst + m * 8) = o1;
    *(bf16x8*)(dst + 64 + m * 8) = o2;
  }
}

// ------- GEMM 256x128 tile, BK=64, 512 thr, depth-2 (R6 proven body) -------
// MODE 0: f32 C row-major. MODE 1: V^T scatter epilogue (col0 = colbase + bx*128).
template <int MODE>
__global__ __launch_bounds__(512, 2) void gemm256(
    const bf16_t* __restrict__ A, const bf16_t* __restrict__ Bw, float* __restrict__ C,
    bf16_t* __restrict__ vto, int M, int N, int K, int nby, int colbase) {
  __shared__ __align__(16) char lds[147456];
  int tid = threadIdx.x;
  int w = tid >> 6, lane = tid & 63;
  int wm = w >> 1, wn = w & 1;
  int mr = lane & 15, kg = lane >> 4;

  int nwg = gridDim.x;
  int orig = blockIdx.x;
  int wgid = (orig & 7) * (nwg >> 3) + (orig >> 3);
  int by = wgid % nby, bx = wgid / nby;
  int row0 = by * 256, col0 = colbase + bx * 128;

  size_t aoff[4], boff[2];
#pragma unroll
  for (int it = 0; it < 4; ++it) {
    int c = tid + it * 512;
    int r = c >> 3;
    int chs = (c & 7) ^ (r & 7);
    aoff[it] = (size_t)(row0 + r) * K + chs * 8;
  }
#pragma unroll
  for (int it = 0; it < 2; ++it) {
    int c = tid + it * 512;
    int r = c >> 3;
    int chs = (c & 7) ^ (r & 7);
    boff[it] = (size_t)(col0 - colbase + r) * K + chs * 8;  // Bw already offset by caller
  }

  auto stageA = [&](int buf, int kt, int half) {
    char* Ad = &lds[buf * 49152];
#pragma unroll
    for (int it = half * 2; it < half * 2 + 2; ++it)
      async_copy16(A + aoff[it] + kt * 64, Ad + (tid + it * 512) * 16);
  };
  auto stageB = [&](int buf, int kt) {
    char* Bd = &lds[buf * 49152 + 32768];
#pragma unroll
    for (int it = 0; it < 2; ++it)
      async_copy16(Bw + boff[it] + kt * 64, Bd + (tid + it * 512) * 16);
  };

  f32x4 zero = {0.f, 0.f, 0.f, 0.f};
  f32x4 acc[4][4];
#pragma unroll
  for (int mi = 0; mi < 4; ++mi)
#pragma unroll
    for (int ni = 0; ni < 4; ++ni) acc[mi][ni] = zero;

  int nt = K >> 6;
  stageA(0, 0, 0); stageA(0, 0, 1); stageB(0, 0);
  stageA(1, 1, 0); stageA(1, 1, 1); stageB(1, 1);
  asm volatile("s_waitcnt vmcnt(6)" ::: "memory");
  __builtin_amdgcn_sched_barrier(0);
  __builtin_amdgcn_s_barrier();
  __builtin_amdgcn_sched_barrier(0);

#pragma unroll 1
  for (int t = 0; t < nt; ++t) {
    int cur = t % 3;
    int nxt = (t + 2) % 3;
    int kt2 = (t + 2 < nt) ? (t + 2) : t;
    const char* Ab = &lds[cur * 49152];
    const char* Bb = &lds[cur * 49152 + 32768];
    bf16x8 af[4][2], bfr[4][2];
#pragma unroll
    for (int mi = 0; mi < 4; ++mi) {
      int row = wm * 64 + mi * 16 + mr;
      const char* rb = Ab + row * 128;
      int sz = (row & 7) << 4;
      af[mi][0] = *(const bf16x8*)(rb + ((kg * 16) ^ sz));
      af[mi][1] = *(const bf16x8*)(rb + ((64 + kg * 16) ^ sz));
    }
#pragma unroll
    for (int ni = 0; ni < 4; ++ni) {
      int row = wn * 64 + ni * 16 + mr;
      const char* rb = Bb + row * 128;
      int sz = (row & 7) << 4;
      bfr[ni][0] = *(const bf16x8*)(rb + ((kg * 16) ^ sz));
      bfr[ni][1] = *(const bf16x8*)(rb + ((64 + kg * 16) ^ sz));
    }
    stageA(nxt, kt2, 0);
    __builtin_amdgcn_s_setprio(1);
#pragma unroll
    for (int mi = 0; mi < 4; ++mi) {
      acc[mi][0] = MFMA16(af[mi][0], bfr[0][0], acc[mi][0]);
      acc[mi][0] = MFMA16(af[mi][1], bfr[0][1], acc[mi][0]);
    }
    __builtin_amdgcn_s_setprio(0);
    stageA(nxt, kt2, 1);
    __builtin_amdgcn_s_setprio(1);
#pragma unroll
    for (int mi = 0; mi < 4; ++mi) {
      acc[mi][1] = MFMA16(af[mi][0], bfr[1][0], acc[mi][1]);
      acc[mi][1] = MFMA16(af[mi][1], bfr[1][1], acc[mi][1]);
    }
    __builtin_amdgcn_s_setprio(0);
    stageB(nxt, kt2);
    __builtin_amdgcn_s_setprio(1);
#pragma unroll
    for (int mi = 0; mi < 4; ++mi) {
      acc[mi][2] = MFMA16(af[mi][0], bfr[2][0], acc[mi][2]);
      acc[mi][2] = MFMA16(af[mi][1], bfr[2][1], acc[mi][2]);
      acc[mi][3] = MFMA16(af[mi][0], bfr[3][0], acc[mi][3]);
      acc[mi][3] = MFMA16(af[mi][1], bfr[3][1], acc[mi][3]);
    }
    __builtin_amdgcn_s_setprio(0);
    asm volatile("s_waitcnt vmcnt(6)" ::: "memory");
    __builtin_amdgcn_sched_barrier(0);
    __builtin_amdgcn_s_barrier();
    __builtin_amdgcn_sched_barrier(0);
  }
  asm volatile("s_waitcnt vmcnt(0)" ::: "memory");
  __syncthreads();

  if (MODE == 0) {
#pragma unroll
    for (int mi = 0; mi < 4; ++mi)
#pragma unroll
      for (int ni = 0; ni < 4; ++ni)
#pragma unroll
        for (int jj = 0; jj < 4; ++jj) {
          int row = row0 + wm * 64 + mi * 16 + kg * 4 + jj;
          int col = col0 + wn * 64 + ni * 16 + mr;
          C[(size_t)row * N + col] = acc[mi][ni][jj];
        }
  } else {
    // ---- v: transposed [d(128)][t(256)] bf16, 512B rows, swizzled (R6 proven) ----
    char* tb = &lds[0];
    int h = (col0 >> 7) & 15;
    int b = row0 >> 11, t0 = row0 & 2047;
#pragma unroll
    for (int mi = 0; mi < 4; ++mi)
#pragma unroll
      for (int ni = 0; ni < 4; ++ni)
#pragma unroll
        for (int jj = 0; jj < 4; ++jj) {
          int rloc = wm * 64 + mi * 16 + kg * 4 + jj;   // t
          int cloc = wn * 64 + ni * 16 + mr;            // d
          *(bf16_t*)(tb + cloc * 512 + ((rloc * 2) ^ ((cloc & 7) << 4))) =
              (bf16_t)acc[mi][ni][jj];
        }
    __syncthreads();
    int d = tid >> 2, qt = tid & 3;
    const char* rowb = tb + d * 512;
    int sz = (d & 7) << 4;
    bf16_t* dst = vto + ((size_t)((b * 16 + h) * 128 + d)) * 2048 + t0 + qt * 64;
#pragma unroll
    for (int m2 = 0; m2 < 8; ++m2)
      *(bf16x8*)(dst + m2 * 8) = *(const bf16x8*)(rowb + ((qt * 128 + m2 * 16) ^ sz));
  }
}

// ---------------- causal flash attention (v2 + T5 setprio) ----------------
__global__ __launch_bounds__(256) void attn_kernel(
    const bf16_t* __restrict__ qg, const bf16_t* __restrict__ kgl,
    const bf16_t* __restrict__ vtg, bf16_t* __restrict__ og) {
  __shared__ __align__(16) bf16_t Ks[2][64 * 128];
  __shared__ __align__(16) bf16_t Vs[2][128 * 64];
  __shared__ __align__(16) bf16_t plds[4][1024];
  const int T = 2048;
  int tid = threadIdx.x;
  int w = tid >> 6, lane = tid & 63;
  int mr = lane & 15, kg = lane >> 4;
  int swz = (mr & 7) << 4;

  int L = blockIdx.y * 16 + blockIdx.x;
  int role = (L & 7) * 64 + (L >> 3);
  int bx = role & 15, bh = role >> 4;

  const bf16_t* Q = qg + (size_t)bh * T * 128;
  const bf16_t* K = kgl + (size_t)bh * T * 128;
  const bf16_t* Vt = vtg + (size_t)bh * 128 * T;

  int sb = tid * 16;
  int krl = sb >> 8;
  int kc = (sb & 255) ^ ((krl & 7) << 4);
  size_t ksrc = (size_t)krl * 128 + (kc >> 1);
  int vdl = sb >> 7;
  int vc = (sb & 127) ^ ((vdl & 7) << 4);
  size_t vsrc = (size_t)vdl * 2048 + (vc >> 1);

  auto stage = [&](int buf, int kb) {
#pragma unroll
    for (int it = 0; it < 4; ++it)
      async_copy16(K + (size_t)(kb + it * 16) * 128 + ksrc, &Ks[buf][it * 2048 + tid * 8]);
#pragma unroll
    for (int it = 0; it < 4; ++it)
      async_copy16(Vt + (size_t)it * 65536 + kb + vsrc, &Vs[buf][it * 2048 + tid * 8]);
  };

  const float cscale = 0.12751744f;  // (1/sqrt(128)) * log2(e)
  f32x4 zero = {0.f, 0.f, 0.f, 0.f};
  bf16_t* P = &plds[w][0];
  int b = bh >> 4, h = bh & 15;

#pragma unroll 1
  for (int ph = 0; ph < 2; ++ph) {
    int qb = ph ? bx : (31 - bx);
    int qr0 = qb * 64 + w * 16;
    bf16x8 qf[4];
#pragma unroll
    for (int db = 0; db < 4; ++db)
      qf[db] = *(const bf16x8*)(Q + (size_t)(qr0 + mr) * 128 + db * 32 + kg * 8);

    f32x4 acc[8];
#pragma unroll
    for (int d2 = 0; d2 < 8; ++d2) acc[d2] = zero;
    float mrun[4] = {-1e30f, -1e30f, -1e30f, -1e30f};
    float lrun[4] = {0.f, 0.f, 0.f, 0.f};

    int nj = qb + 1;
    __syncthreads();
    stage(0, 0);
    int cur = 0;
#pragma unroll 1
    for (int j = 0; j < nj; ++j) {
      __syncthreads();
      if (j + 1 < nj) stage(cur ^ 1, (j + 1) * 64);
      const char* KsB = (const char*)&Ks[cur][0];
      const char* VsB = (const char*)&Vs[cur][0];
      int kb = j * 64;
      f32x4 s[4];
      __builtin_amdgcn_s_setprio(1);
#pragma unroll
      for (int ntl = 0; ntl < 4; ++ntl) {
        s[ntl] = zero;
        int rowb = (ntl * 16 + mr) * 256;
#pragma unroll
        for (int db = 0; db < 4; ++db) {
          bf16x8 kf = *(const bf16x8*)(KsB + rowb + ((db * 64 + kg * 16) ^ swz));
          s[ntl] = MFMA16(qf[db], kf, s[ntl]);
        }
      }
      __builtin_amdgcn_s_setprio(0);
      float pvv[4][4];
      float tmax[4] = {-3e38f, -3e38f, -3e38f, -3e38f};
      bool diag = (j == qb);
#pragma unroll
      for (int ntl = 0; ntl < 4; ++ntl)
#pragma unroll
        for (int jj = 0; jj < 4; ++jj) {
          float v = s[ntl][jj] * cscale;
          if (diag && (kb + ntl * 16 + mr) > (qr0 + kg * 4 + jj)) v = -1e30f;
          pvv[ntl][jj] = v;
          tmax[jj] = fmaxf(tmax[jj], v);
        }
#pragma unroll
      for (int m = 1; m < 16; m <<= 1)
#pragma unroll
        for (int jj = 0; jj < 4; ++jj)
          tmax[jj] = fmaxf(tmax[jj], __shfl_xor(tmax[jj], m, 64));
      bool ok = true;
#pragma unroll
      for (int jj = 0; jj < 4; ++jj) ok &= (tmax[jj] <= mrun[jj] + 8.0f);
      if (!__all(ok)) {
#pragma unroll
        for (int jj = 0; jj < 4; ++jj) {
          float mn = fmaxf(mrun[jj], tmax[jj]);
          float corr = __builtin_amdgcn_exp2f(mrun[jj] - mn);
          mrun[jj] = mn;
          lrun[jj] *= corr;
#pragma unroll
          for (int d2 = 0; d2 < 8; ++d2) acc[d2][jj] *= corr;
        }
      }
      float rs[4] = {0.f, 0.f, 0.f, 0.f};
#pragma unroll
      for (int ntl = 0; ntl < 4; ++ntl)
#pragma unroll
        for (int jj = 0; jj < 4; ++jj) {
          float p = __builtin_amdgcn_exp2f(pvv[ntl][jj] - mrun[jj]);
          pvv[ntl][jj] = p;
          rs[jj] += p;
        }
#pragma unroll
      for (int m = 1; m < 16; m <<= 1)
#pragma unroll
        for (int jj = 0; jj < 4; ++jj) rs[jj] += __shfl_xor(rs[jj], m, 64);
#pragma unroll
      for (int jj = 0; jj < 4; ++jj) lrun[jj] += rs[jj];
#pragma unroll
      for (int ntl = 0; ntl < 4; ++ntl)
#pragma unroll
        for (int jj = 0; jj < 4; ++jj) {
          int rr = kg * 4 + jj;
          int cbyte = (mr + ntl * 16) * 2;
          *(bf16_t*)((char*)P + rr * 128 + (cbyte ^ ((rr & 7) << 4))) = (bf16_t)pvv[ntl][jj];
        }
      __builtin_amdgcn_s_setprio(1);
#pragma unroll
      for (int ks = 0; ks < 2; ++ks) {
        int cb = (ks * 32 + kg * 8) * 2;
        bf16x8 pa = *(const bf16x8*)((const char*)P + mr * 128 + (cb ^ ((mr & 7) << 4)));
#pragma unroll
        for (int d2 = 0; d2 < 8; ++d2) {
          bf16x8 vf = *(const bf16x8*)(VsB + (d2 * 16 + mr) * 128 + ((ks * 64 + kg * 16) ^ swz));
          acc[d2] = MFMA16(pa, vf, acc[d2]);
        }
      }
      __builtin_amdgcn_s_setprio(0);
      cur ^= 1;
    }
#pragma unroll
    for (int jj = 0; jj < 4; ++jj) {
      float invl = 1.0f / lrun[jj];
      int t = qr0 + kg * 4 + jj;
      size_t row = (size_t)b * 2048 + h * 128 + (t >> 4);
      bf16_t* orow = og + row * 2048 + (t & 15) * 128;
#pragma unroll
      for (int d2 = 0; d2 < 8; ++d2)
        orow[d2 * 16 + mr] = (bf16_t)(acc[d2][jj] * invl);
    }
  }
}

extern "C" void kernel_launch(void* const* d_in, const int* in_sizes, int n_in,
                              void* d_out, int out_size, void* d_ws, size_t ws_size,
                              hipStream_t stream) {
  const float* x = (const float*)d_in[0];      // [2,2048,2048]
  const float* wqkv = (const float*)d_in[1];   // [6144,2048]
  const float* wproj = (const float*)d_in[2];  // [2048,2048]
  float* out = (float*)d_out;                  // [2,2048,2048]
  char* ws = (char*)d_ws;

  const size_t OFF_WQKV = 16777216;
  const size_t OFF_Q = 41943040;
  const size_t OFF_K = 58720256;
  const size_t OFF_VT = 75497472;

  bf16_t* xb = (bf16_t*)(ws);
  bf16_t* wqkvb = (bf16_t*)(ws + OFF_WQKV);
  bf16_t* g_q = (bf16_t*)(ws + OFF_Q);
  bf16_t* g_k = (bf16_t*)(ws + OFF_K);
  bf16_t* g_vt = (bf16_t*)(ws + OFF_VT);
  bf16_t* g_att = (bf16_t*)(ws);               // alias xb (dead after gemm1)
  bf16_t* wprojb = (bf16_t*)(ws + OFF_WQKV);   // alias wqkvb (dead after gemm1)

  cast_f32_bf16<<<2048, 256, 0, stream>>>(x, xb, 8388608 / 8);
  cast_f32_bf16<<<2048, 256, 0, stream>>>(wqkv, wqkvb, 12582912 / 8);
  // d1: q,k columns (N=4096) as 256^2 tiles -> 256 blocks = 1 full CU round
  gemm_qkv<<<256, 512, 0, stream>>>(xb, wqkvb, g_q, g_k, 2048);
  // d2: v columns (N=2048) as 256x128 tiles -> 256 blocks = 1 full CU round
  gemm256<1><<<256, 512, 0, stream>>>(xb, wqkvb + (size_t)4096 * 2048, nullptr, g_vt,
                                      4096, 2048, 2048, 16, 4096);
  cast_f32_bf16<<<2048, 256, 0, stream>>>(wproj, wprojb, 4194304 / 8);
  attn_kernel<<<dim3(16, 32), 256, 0, stream>>>(g_q, g_k, g_vt, g_att);
  // output projection (256x128 tiles, 256 blocks = 1 full CU round)
  gemm256<0><<<256, 512, 0, stream>>>(g_att, wprojb, out, nullptr, 4096, 2048, 2048, 16, 0);
}

// Round 10
// 246.427 us; speedup vs baseline: 1.1609x; 1.0840x over previous
//
#include <hip/hip_runtime.h>
#include <hip/hip_bf16.h>

typedef __bf16 bf16_t;
typedef __bf16 bf16x8 __attribute__((ext_vector_type(8)));
typedef float f32x4 __attribute__((ext_vector_type(4)));

#define MFMA16(a, b, c) __builtin_amdgcn_mfma_f32_16x16x32_bf16(a, b, c, 0, 0, 0)

__device__ __forceinline__ void async_copy16(const void* g, void* l) {
  __builtin_amdgcn_global_load_lds(
      (const __attribute__((address_space(1))) void*)g,
      (__attribute__((address_space(3))) void*)l, 16, 0, 0);
}

// ---------------- cast f32 -> bf16 (8 elems/thread) ----------------
__global__ void cast_f32_bf16(const float* __restrict__ in, bf16_t* __restrict__ out, int n8) {
  int stride = gridDim.x * blockDim.x;
  for (int i = blockIdx.x * blockDim.x + threadIdx.x; i < n8; i += stride) {
    const float* p = in + (size_t)i * 8;
    f32x4 a = *(const f32x4*)p;
    f32x4 b = *(const f32x4*)(p + 4);
    bf16x8 o;
    o[0] = (bf16_t)a[0]; o[1] = (bf16_t)a[1]; o[2] = (bf16_t)a[2]; o[3] = (bf16_t)a[3];
    o[4] = (bf16_t)b[0]; o[5] = (bf16_t)b[1]; o[6] = (bf16_t)b[2]; o[7] = (bf16_t)b[3];
    *(bf16x8*)(out + (size_t)i * 8) = o;
  }
}

// ======== GEMM-QK: 256x256, BK=64, 512thr (8 waves 2Mx4N), 4-phase (R8 body) ========
__global__ __launch_bounds__(512, 2) void gemm_qkv(
    const bf16_t* __restrict__ A, const bf16_t* __restrict__ Bw,
    bf16_t* __restrict__ qo, bf16_t* __restrict__ ko,
    int K) {
  __shared__ __align__(16) char lds[131072];
  int tid = threadIdx.x;
  int w = tid >> 6, lane = tid & 63;
  int wm = w & 1, wn = w >> 1;
  int mr = lane & 15, kg = lane >> 4;

  int orig = blockIdx.x;
  int chunk = orig & 7, i = orig >> 3;
  int by = (chunk & 3) * 4 + (i & 3);
  int bx = (chunk >> 2) * 8 + (i >> 2);
  int row0 = by * 256, col0 = bx * 256;

  int lr = tid >> 3, ch = (tid & 7) ^ (lr & 7);
  size_t aoff[4], boff[4];
#pragma unroll
  for (int g = 0; g < 4; ++g) {
    int gr = g * 32 + (lr & 31) + (lr >> 5) * 128;
    aoff[g] = (size_t)(row0 + gr) * K + ch * 8;
  }
#pragma unroll
  for (int p = 0; p < 4; ++p) {
    int gr = (lr >> 4) * 64 + p * 16 + (lr & 15);
    boff[p] = (size_t)(col0 + gr) * K + ch * 8;
  }

  auto stgA = [&](int q, int g, int kt) {
    async_copy16(A + aoff[g] + kt * 64, lds + q * 65536 + g * 8192 + tid * 16);
  };
  auto stgB = [&](int q, int p, int kt) {
    async_copy16(Bw + boff[p] + kt * 64, lds + q * 65536 + 32768 + p * 8192 + tid * 16);
  };

  f32x4 zero = {0.f, 0.f, 0.f, 0.f};
  f32x4 acc[8][4];
#pragma unroll
  for (int mi = 0; mi < 8; ++mi)
#pragma unroll
    for (int ni = 0; ni < 4; ++ni) acc[mi][ni] = zero;

  int nt = K >> 6;  // 32

  stgB(0, 0, 0); stgB(0, 1, 0); stgB(0, 2, 0); stgB(0, 3, 0);
  stgA(0, 0, 0); stgA(0, 1, 0); stgA(0, 2, 0); stgA(0, 3, 0);
  asm volatile("s_waitcnt vmcnt(0)" ::: "memory");
  __builtin_amdgcn_sched_barrier(0);
  __builtin_amdgcn_s_barrier();
  __builtin_amdgcn_sched_barrier(0);

#pragma unroll 1
  for (int t = 0; t < nt; ++t) {
    int q = t & 1, qn = q ^ 1;
    int kt = (t + 1 < nt) ? (t + 1) : t;
    const char* Ab = lds + q * 65536;
    const char* Bb = Ab + 32768;
    bf16x8 bf[4][2];

#define QKV_PHASE(MI0, STG0, STG1, WAIT)                                        \
    {                                                                           \
      int r0 = ((MI0) >> 1) * 64 + wm * 32 + mr;                                \
      int r1 = r0 + 16;                                                         \
      bf16x8 a00 = *(const bf16x8*)(Ab + r0 * 128 + ((kg * 16) ^ ((r0 & 7) << 4)));      \
      bf16x8 a01 = *(const bf16x8*)(Ab + r0 * 128 + ((64 + kg * 16) ^ ((r0 & 7) << 4))); \
      bf16x8 a10 = *(const bf16x8*)(Ab + r1 * 128 + ((kg * 16) ^ ((r1 & 7) << 4)));      \
      bf16x8 a11 = *(const bf16x8*)(Ab + r1 * 128 + ((64 + kg * 16) ^ ((r1 & 7) << 4))); \
      STG0; STG1;                                                               \
      __builtin_amdgcn_sched_barrier(0);                                        \
      asm volatile("s_waitcnt vmcnt(" #WAIT ")" ::: "memory");                  \
      __builtin_amdgcn_s_barrier();                                             \
      asm volatile("s_waitcnt lgkmcnt(0)" ::: "memory");                        \
      __builtin_amdgcn_sched_barrier(0);                                        \
      __builtin_amdgcn_s_setprio(1);                                            \
      _Pragma("unroll")                                                         \
      for (int ni = 0; ni < 4; ++ni) {                                          \
        acc[MI0][ni] = MFMA16(a00, bf[ni][0], acc[MI0][ni]);                    \
        acc[MI0][ni] = MFMA16(a01, bf[ni][1], acc[MI0][ni]);                    \
        acc[(MI0) + 1][ni] = MFMA16(a10, bf[ni][0], acc[(MI0) + 1][ni]);        \
        acc[(MI0) + 1][ni] = MFMA16(a11, bf[ni][1], acc[(MI0) + 1][ni]);        \
      }                                                                         \
      __builtin_amdgcn_s_setprio(0);                                            \
      __builtin_amdgcn_sched_barrier(0);                                        \
      __builtin_amdgcn_s_barrier();                                             \
      __builtin_amdgcn_sched_barrier(0);                                        \
    }

#pragma unroll
    for (int ni = 0; ni < 4; ++ni) {
      int rb = ni * 64 + wn * 16 + mr;
      bf[ni][0] = *(const bf16x8*)(Bb + rb * 128 + ((kg * 16) ^ ((rb & 7) << 4)));
      bf[ni][1] = *(const bf16x8*)(Bb + rb * 128 + ((64 + kg * 16) ^ ((rb & 7) << 4)));
    }
    QKV_PHASE(0, stgB(qn, 0, kt), stgB(qn, 1, kt), 4)
    QKV_PHASE(2, stgB(qn, 2, kt), stgB(qn, 3, kt), 5)
    QKV_PHASE(4, stgA(qn, 0, kt), stgA(qn, 1, kt), 6)
    QKV_PHASE(6, stgA(qn, 2, kt), stgA(qn, 3, kt), 3)
#undef QKV_PHASE
  }
  asm volatile("s_waitcnt vmcnt(0)" ::: "memory");
  __syncthreads();

  // ---- fused RoPE epilogue ----
  char* tb = &lds[0];
  int s = col0 >> 11;
  int h0 = (col0 >> 7) & 15;
  int b = row0 >> 11, t0 = row0 & 2047;
#pragma unroll
  for (int mi = 0; mi < 8; ++mi)
#pragma unroll
    for (int ni = 0; ni < 4; ++ni)
#pragma unroll
      for (int jj = 0; jj < 4; ++jj) {
        int rl = wm * 128 + mi * 16 + kg * 4 + jj;
        int cb = (wn * 64 + ni * 16 + mr) * 2;
        *(bf16_t*)(tb + rl * 512 + (cb ^ ((rl & 7) << 4))) = (bf16_t)acc[mi][ni][jj];
      }
  __syncthreads();
  int r = tid >> 1, hs = tid & 1;
  const char* rowb = tb + r * 512;
  int sz = (r & 7) << 4;
  int t = t0 + r;
  bf16_t* dst = (s == 0 ? qo : ko) + ((size_t)((b * 16 + h0 + hs) * 2048 + t)) * 128;
  float tf = (float)t;
  const float cinv = -0.20762050593046014f;  // -log2(10000)/64
  bf16x8 vin[16];
#pragma unroll
  for (int m = 0; m < 16; ++m)
    vin[m] = *(const bf16x8*)(rowb + ((hs * 256 + m * 16) ^ sz));
#pragma unroll
  for (int m = 0; m < 8; ++m) {
    bf16x8 o1, o2;
#pragma unroll
    for (int e = 0; e < 8; ++e) {
      float ang = tf * exp2f((float)(m * 8 + e) * cinv);
      float sv = __sinf(ang), cv = __cosf(ang);
      float x1 = (float)vin[m][e], x2 = (float)vin[m + 8][e];
      o1[e] = (bf16_t)(x1 * cv - x2 * sv);
      o2[e] = (bf16_t)(x2 * cv + x1 * sv);
    }
    *(bf16x8*)(dst + m * 8) = o1;
    *(bf16x8*)(dst + 64 + m * 8) = o2;
  }
}

// ------- GEMM 256x128 tile, BK=64, 512 thr, depth-2 (R6 proven body) -------
template <int MODE>
__global__ __launch_bounds__(512, 2) void gemm256(
    const bf16_t* __restrict__ A, const bf16_t* __restrict__ Bw, float* __restrict__ C,
    bf16_t* __restrict__ vto, int M, int N, int K, int nby, int colbase) {
  __shared__ __align__(16) char lds[147456];
  int tid = threadIdx.x;
  int w = tid >> 6, lane = tid & 63;
  int wm = w >> 1, wn = w & 1;
  int mr = lane & 15, kg = lane >> 4;

  int nwg = gridDim.x;
  int orig = blockIdx.x;
  int wgid = (orig & 7) * (nwg >> 3) + (orig >> 3);
  int by = wgid % nby, bx = wgid / nby;
  int row0 = by * 256, col0 = colbase + bx * 128;

  size_t aoff[4], boff[2];
#pragma unroll
  for (int it = 0; it < 4; ++it) {
    int c = tid + it * 512;
    int r = c >> 3;
    int chs = (c & 7) ^ (r & 7);
    aoff[it] = (size_t)(row0 + r) * K + chs * 8;
  }
#pragma unroll
  for (int it = 0; it < 2; ++it) {
    int c = tid + it * 512;
    int r = c >> 3;
    int chs = (c & 7) ^ (r & 7);
    boff[it] = (size_t)(col0 - colbase + r) * K + chs * 8;
  }

  auto stageA = [&](int buf, int kt, int half) {
    char* Ad = &lds[buf * 49152];
#pragma unroll
    for (int it = half * 2; it < half * 2 + 2; ++it)
      async_copy16(A + aoff[it] + kt * 64, Ad + (tid + it * 512) * 16);
  };
  auto stageB = [&](int buf, int kt) {
    char* Bd = &lds[buf * 49152 + 32768];
#pragma unroll
    for (int it = 0; it < 2; ++it)
      async_copy16(Bw + boff[it] + kt * 64, Bd + (tid + it * 512) * 16);
  };

  f32x4 zero = {0.f, 0.f, 0.f, 0.f};
  f32x4 acc[4][4];
#pragma unroll
  for (int mi = 0; mi < 4; ++mi)
#pragma unroll
    for (int ni = 0; ni < 4; ++ni) acc[mi][ni] = zero;

  int nt = K >> 6;
  stageA(0, 0, 0); stageA(0, 0, 1); stageB(0, 0);
  stageA(1, 1, 0); stageA(1, 1, 1); stageB(1, 1);
  asm volatile("s_waitcnt vmcnt(6)" ::: "memory");
  __builtin_amdgcn_sched_barrier(0);
  __builtin_amdgcn_s_barrier();
  __builtin_amdgcn_sched_barrier(0);

#pragma unroll 1
  for (int t = 0; t < nt; ++t) {
    int cur = t % 3;
    int nxt = (t + 2) % 3;
    int kt2 = (t + 2 < nt) ? (t + 2) : t;
    const char* Ab = &lds[cur * 49152];
    const char* Bb = &lds[cur * 49152 + 32768];
    bf16x8 af[4][2], bfr[4][2];
#pragma unroll
    for (int mi = 0; mi < 4; ++mi) {
      int row = wm * 64 + mi * 16 + mr;
      const char* rb = Ab + row * 128;
      int sz = (row & 7) << 4;
      af[mi][0] = *(const bf16x8*)(rb + ((kg * 16) ^ sz));
      af[mi][1] = *(const bf16x8*)(rb + ((64 + kg * 16) ^ sz));
    }
#pragma unroll
    for (int ni = 0; ni < 4; ++ni) {
      int row = wn * 64 + ni * 16 + mr;
      const char* rb = Bb + row * 128;
      int sz = (row & 7) << 4;
      bfr[ni][0] = *(const bf16x8*)(rb + ((kg * 16) ^ sz));
      bfr[ni][1] = *(const bf16x8*)(rb + ((64 + kg * 16) ^ sz));
    }
    stageA(nxt, kt2, 0);
    __builtin_amdgcn_s_setprio(1);
#pragma unroll
    for (int mi = 0; mi < 4; ++mi) {
      acc[mi][0] = MFMA16(af[mi][0], bfr[0][0], acc[mi][0]);
      acc[mi][0] = MFMA16(af[mi][1], bfr[0][1], acc[mi][0]);
    }
    __builtin_amdgcn_s_setprio(0);
    stageA(nxt, kt2, 1);
    __builtin_amdgcn_s_setprio(1);
#pragma unroll
    for (int mi = 0; mi < 4; ++mi) {
      acc[mi][1] = MFMA16(af[mi][0], bfr[1][0], acc[mi][1]);
      acc[mi][1] = MFMA16(af[mi][1], bfr[1][1], acc[mi][1]);
    }
    __builtin_amdgcn_s_setprio(0);
    stageB(nxt, kt2);
    __builtin_amdgcn_s_setprio(1);
#pragma unroll
    for (int mi = 0; mi < 4; ++mi) {
      acc[mi][2] = MFMA16(af[mi][0], bfr[2][0], acc[mi][2]);
      acc[mi][2] = MFMA16(af[mi][1], bfr[2][1], acc[mi][2]);
      acc[mi][3] = MFMA16(af[mi][0], bfr[3][0], acc[mi][3]);
      acc[mi][3] = MFMA16(af[mi][1], bfr[3][1], acc[mi][3]);
    }
    __builtin_amdgcn_s_setprio(0);
    asm volatile("s_waitcnt vmcnt(6)" ::: "memory");
    __builtin_amdgcn_sched_barrier(0);
    __builtin_amdgcn_s_barrier();
    __builtin_amdgcn_sched_barrier(0);
  }
  asm volatile("s_waitcnt vmcnt(0)" ::: "memory");
  __syncthreads();

  if (MODE == 0) {
#pragma unroll
    for (int mi = 0; mi < 4; ++mi)
#pragma unroll
      for (int ni = 0; ni < 4; ++ni)
#pragma unroll
        for (int jj = 0; jj < 4; ++jj) {
          int row = row0 + wm * 64 + mi * 16 + kg * 4 + jj;
          int col = col0 + wn * 64 + ni * 16 + mr;
          C[(size_t)row * N + col] = acc[mi][ni][jj];
        }
  } else {
    char* tb = &lds[0];
    int h = (col0 >> 7) & 15;
    int b = row0 >> 11, t0 = row0 & 2047;
#pragma unroll
    for (int mi = 0; mi < 4; ++mi)
#pragma unroll
      for (int ni = 0; ni < 4; ++ni)
#pragma unroll
        for (int jj = 0; jj < 4; ++jj) {
          int rloc = wm * 64 + mi * 16 + kg * 4 + jj;
          int cloc = wn * 64 + ni * 16 + mr;
          *(bf16_t*)(tb + cloc * 512 + ((rloc * 2) ^ ((cloc & 7) << 4))) =
              (bf16_t)acc[mi][ni][jj];
        }
    __syncthreads();
    int d = tid >> 2, qt = tid & 3;
    const char* rowb = tb + d * 512;
    int sz = (d & 7) << 4;
    bf16_t* dst = vto + ((size_t)((b * 16 + h) * 128 + d)) * 2048 + t0 + qt * 64;
#pragma unroll
    for (int m2 = 0; m2 < 8; ++m2)
      *(bf16x8*)(dst + m2 * 8) = *(const bf16x8*)(rowb + ((qt * 128 + m2 * 16) ^ sz));
  }
}

// ---------------- causal flash attention (v3: chain-free fast path) ----------------
// Changes vs v2: (1) defer-max trigger uses per-lane max + __all (no shuffle reduce
// on fast path; full reduce only inside rescale branch); (2) l kept as per-lane
// partial, reduced ONCE in epilogue (exact: corr rescale is linear).
__global__ __launch_bounds__(256) void attn_kernel(
    const bf16_t* __restrict__ qg, const bf16_t* __restrict__ kgl,
    const bf16_t* __restrict__ vtg, bf16_t* __restrict__ og) {
  __shared__ __align__(16) bf16_t Ks[2][64 * 128];
  __shared__ __align__(16) bf16_t Vs[2][128 * 64];
  __shared__ __align__(16) bf16_t plds[4][1024];
  const int T = 2048;
  int tid = threadIdx.x;
  int w = tid >> 6, lane = tid & 63;
  int mr = lane & 15, kg = lane >> 4;
  int swz = (mr & 7) << 4;

  int L = blockIdx.y * 16 + blockIdx.x;
  int role = (L & 7) * 64 + (L >> 3);
  int bx = role & 15, bh = role >> 4;

  const bf16_t* Q = qg + (size_t)bh * T * 128;
  const bf16_t* K = kgl + (size_t)bh * T * 128;
  const bf16_t* Vt = vtg + (size_t)bh * 128 * T;

  int sb = tid * 16;
  int krl = sb >> 8;
  int kc = (sb & 255) ^ ((krl & 7) << 4);
  size_t ksrc = (size_t)krl * 128 + (kc >> 1);
  int vdl = sb >> 7;
  int vc = (sb & 127) ^ ((vdl & 7) << 4);
  size_t vsrc = (size_t)vdl * 2048 + (vc >> 1);

  auto stage = [&](int buf, int kb) {
#pragma unroll
    for (int it = 0; it < 4; ++it)
      async_copy16(K + (size_t)(kb + it * 16) * 128 + ksrc, &Ks[buf][it * 2048 + tid * 8]);
#pragma unroll
    for (int it = 0; it < 4; ++it)
      async_copy16(Vt + (size_t)it * 65536 + kb + vsrc, &Vs[buf][it * 2048 + tid * 8]);
  };

  const float cscale = 0.12751744f;  // (1/sqrt(128)) * log2(e)
  f32x4 zero = {0.f, 0.f, 0.f, 0.f};
  bf16_t* P = &plds[w][0];
  int b = bh >> 4, h = bh & 15;

#pragma unroll 1
  for (int ph = 0; ph < 2; ++ph) {
    int qb = ph ? bx : (31 - bx);
    int qr0 = qb * 64 + w * 16;
    bf16x8 qf[4];
#pragma unroll
    for (int db = 0; db < 4; ++db)
      qf[db] = *(const bf16x8*)(Q + (size_t)(qr0 + mr) * 128 + db * 32 + kg * 8);

    f32x4 acc[8];
#pragma unroll
    for (int d2 = 0; d2 < 8; ++d2) acc[d2] = zero;
    float mrun[4] = {-1e30f, -1e30f, -1e30f, -1e30f};
    float lpart[4] = {0.f, 0.f, 0.f, 0.f};  // per-lane partial row-sum

    int nj = qb + 1;
    __syncthreads();
    stage(0, 0);
    int cur = 0;
#pragma unroll 1
    for (int j = 0; j < nj; ++j) {
      __syncthreads();
      if (j + 1 < nj) stage(cur ^ 1, (j + 1) * 64);
      const char* KsB = (const char*)&Ks[cur][0];
      const char* VsB = (const char*)&Vs[cur][0];
      int kb = j * 64;
      f32x4 s[4];
      __builtin_amdgcn_s_setprio(1);
#pragma unroll
      for (int ntl = 0; ntl < 4; ++ntl) {
        s[ntl] = zero;
        int rowb = (ntl * 16 + mr) * 256;
#pragma unroll
        for (int db = 0; db < 4; ++db) {
          bf16x8 kf = *(const bf16x8*)(KsB + rowb + ((db * 64 + kg * 16) ^ swz));
          s[ntl] = MFMA16(qf[db], kf, s[ntl]);
        }
      }
      __builtin_amdgcn_s_setprio(0);
      // ---- scale + mask + PER-LANE max (no shuffle on fast path) ----
      float pvv[4][4];
      float lmax[4] = {-3e38f, -3e38f, -3e38f, -3e38f};
      bool diag = (j == qb);
#pragma unroll
      for (int ntl = 0; ntl < 4; ++ntl)
#pragma unroll
        for (int jj = 0; jj < 4; ++jj) {
          float v = s[ntl][jj] * cscale;
          if (diag && (kb + ntl * 16 + mr) > (qr0 + kg * 4 + jj)) v = -1e30f;
          pvv[ntl][jj] = v;
          lmax[jj] = fmaxf(lmax[jj], v);
        }
      // ---- defer-max: rowmax<=mrun+8  <=>  __all(lanemax<=mrun+8) ----
      bool ok = true;
#pragma unroll
      for (int jj = 0; jj < 4; ++jj) ok &= (lmax[jj] <= mrun[jj] + 8.0f);
      if (!__all(ok)) {
        float tmax[4];
#pragma unroll
        for (int jj = 0; jj < 4; ++jj) tmax[jj] = lmax[jj];
#pragma unroll
        for (int m = 1; m < 16; m <<= 1)
#pragma unroll
          for (int jj = 0; jj < 4; ++jj)
            tmax[jj] = fmaxf(tmax[jj], __shfl_xor(tmax[jj], m, 64));
#pragma unroll
        for (int jj = 0; jj < 4; ++jj) {
          float mn = fmaxf(mrun[jj], tmax[jj]);
          float corr = __builtin_amdgcn_exp2f(mrun[jj] - mn);
          mrun[jj] = mn;
          lpart[jj] *= corr;
#pragma unroll
          for (int d2 = 0; d2 < 8; ++d2) acc[d2][jj] *= corr;
        }
      }
      // ---- exp + per-lane partial sum (no per-tile reduce) ----
#pragma unroll
      for (int ntl = 0; ntl < 4; ++ntl)
#pragma unroll
        for (int jj = 0; jj < 4; ++jj) {
          float p = __builtin_amdgcn_exp2f(pvv[ntl][jj] - mrun[jj]);
          pvv[ntl][jj] = p;
          lpart[jj] += p;
        }
#pragma unroll
      for (int ntl = 0; ntl < 4; ++ntl)
#pragma unroll
        for (int jj = 0; jj < 4; ++jj) {
          int rr = kg * 4 + jj;
          int cbyte = (mr + ntl * 16) * 2;
          *(bf16_t*)((char*)P + rr * 128 + (cbyte ^ ((rr & 7) << 4))) = (bf16_t)pvv[ntl][jj];
        }
      __builtin_amdgcn_s_setprio(1);
#pragma unroll
      for (int ks = 0; ks < 2; ++ks) {
        int cb = (ks * 32 + kg * 8) * 2;
        bf16x8 pa = *(const bf16x8*)((const char*)P + mr * 128 + (cb ^ ((mr & 7) << 4)));
#pragma unroll
        for (int d2 = 0; d2 < 8; ++d2) {
          bf16x8 vf = *(const bf16x8*)(VsB + (d2 * 16 + mr) * 128 + ((ks * 64 + kg * 16) ^ swz));
          acc[d2] = MFMA16(pa, vf, acc[d2]);
        }
      }
      __builtin_amdgcn_s_setprio(0);
      cur ^= 1;
    }
    // ---- epilogue: ONE l-reduction per phase, then O /= l, store ----
#pragma unroll
    for (int m = 1; m < 16; m <<= 1)
#pragma unroll
      for (int jj = 0; jj < 4; ++jj) lpart[jj] += __shfl_xor(lpart[jj], m, 64);
#pragma unroll
    for (int jj = 0; jj < 4; ++jj) {
      float invl = 1.0f / lpart[jj];
      int t = qr0 + kg * 4 + jj;
      size_t row = (size_t)b * 2048 + h * 128 + (t >> 4);
      bf16_t* orow = og + row * 2048 + (t & 15) * 128;
#pragma unroll
      for (int d2 = 0; d2 < 8; ++d2)
        orow[d2 * 16 + mr] = (bf16_t)(acc[d2][jj] * invl);
    }
  }
}

extern "C" void kernel_launch(void* const* d_in, const int* in_sizes, int n_in,
                              void* d_out, int out_size, void* d_ws, size_t ws_size,
                              hipStream_t stream) {
  const float* x = (const float*)d_in[0];      // [2,2048,2048]
  const float* wqkv = (const float*)d_in[1];   // [6144,2048]
  const float* wproj = (const float*)d_in[2];  // [2048,2048]
  float* out = (float*)d_out;                  // [2,2048,2048]
  char* ws = (char*)d_ws;

  const size_t OFF_WQKV = 16777216;
  const size_t OFF_Q = 41943040;
  const size_t OFF_K = 58720256;
  const size_t OFF_VT = 75497472;

  bf16_t* xb = (bf16_t*)(ws);
  bf16_t* wqkvb = (bf16_t*)(ws + OFF_WQKV);
  bf16_t* g_q = (bf16_t*)(ws + OFF_Q);
  bf16_t* g_k = (bf16_t*)(ws + OFF_K);
  bf16_t* g_vt = (bf16_t*)(ws + OFF_VT);
  bf16_t* g_att = (bf16_t*)(ws);               // alias xb (dead after gemm1)
  bf16_t* wprojb = (bf16_t*)(ws + OFF_WQKV);   // alias wqkvb (dead after gemm1)

  cast_f32_bf16<<<2048, 256, 0, stream>>>(x, xb, 8388608 / 8);
  cast_f32_bf16<<<2048, 256, 0, stream>>>(wqkv, wqkvb, 12582912 / 8);
  // d1: q,k columns (N=4096) as 256^2 tiles -> 256 blocks = 1 full CU round
  gemm_qkv<<<256, 512, 0, stream>>>(xb, wqkvb, g_q, g_k, 2048);
  // d2: v columns (N=2048) as 256x128 tiles -> 256 blocks = 1 full CU round
  gemm256<1><<<256, 512, 0, stream>>>(xb, wqkvb + (size_t)4096 * 2048, nullptr, g_vt,
                                      4096, 2048, 2048, 16, 4096);
  cast_f32_bf16<<<2048, 256, 0, stream>>>(wproj, wprojb, 4194304 / 8);
  attn_kernel<<<dim3(16, 32), 256, 0, stream>>>(g_q, g_k, g_vt, g_att);
  // output projection (256x128 tiles, 256 blocks = 1 full CU round)
  gemm256<0><<<256, 512, 0, stream>>>(g_att, wprojb, out, nullptr, 4096, 2048, 2048, 16, 0);
}

// Round 11
// 245.702 us; speedup vs baseline: 1.1644x; 1.0030x over previous
//
#include <hip/hip_runtime.h>
#include <hip/hip_bf16.h>

typedef __bf16 bf16_t;
typedef __bf16 bf16x8 __attribute__((ext_vector_type(8)));
typedef float f32x4 __attribute__((ext_vector_type(4)));

#define MFMA16(a, b, c) __builtin_amdgcn_mfma_f32_16x16x32_bf16(a, b, c, 0, 0, 0)

__device__ __forceinline__ void async_copy16(const void* g, void* l) {
  __builtin_amdgcn_global_load_lds(
      (const __attribute__((address_space(1))) void*)g,
      (__attribute__((address_space(3))) void*)l, 16, 0, 0);
}

// ---------------- cast f32 -> bf16 (8 elems/thread) ----------------
__global__ void cast_f32_bf16(const float* __restrict__ in, bf16_t* __restrict__ out, int n8) {
  int stride = gridDim.x * blockDim.x;
  for (int i = blockIdx.x * blockDim.x + threadIdx.x; i < n8; i += stride) {
    const float* p = in + (size_t)i * 8;
    f32x4 a = *(const f32x4*)p;
    f32x4 b = *(const f32x4*)(p + 4);
    bf16x8 o;
    o[0] = (bf16_t)a[0]; o[1] = (bf16_t)a[1]; o[2] = (bf16_t)a[2]; o[3] = (bf16_t)a[3];
    o[4] = (bf16_t)b[0]; o[5] = (bf16_t)b[1]; o[6] = (bf16_t)b[2]; o[7] = (bf16_t)b[3];
    *(bf16x8*)(out + (size_t)i * 8) = o;
  }
}

// ======== GEMM-QK: 256x256, BK=64, 512thr (8 waves 2Mx4N), 4-phase (R8 body) ========
// q outputs PRE-SCALED by (1/sqrt(128))*log2(e) so attn's softmax needs no scale mul.
__global__ __launch_bounds__(512, 2) void gemm_qkv(
    const bf16_t* __restrict__ A, const bf16_t* __restrict__ Bw,
    bf16_t* __restrict__ qo, bf16_t* __restrict__ ko,
    int K) {
  __shared__ __align__(16) char lds[131072];
  int tid = threadIdx.x;
  int w = tid >> 6, lane = tid & 63;
  int wm = w & 1, wn = w >> 1;
  int mr = lane & 15, kg = lane >> 4;

  int orig = blockIdx.x;
  int chunk = orig & 7, i = orig >> 3;
  int by = (chunk & 3) * 4 + (i & 3);
  int bx = (chunk >> 2) * 8 + (i >> 2);
  int row0 = by * 256, col0 = bx * 256;

  int lr = tid >> 3, ch = (tid & 7) ^ (lr & 7);
  size_t aoff[4], boff[4];
#pragma unroll
  for (int g = 0; g < 4; ++g) {
    int gr = g * 32 + (lr & 31) + (lr >> 5) * 128;
    aoff[g] = (size_t)(row0 + gr) * K + ch * 8;
  }
#pragma unroll
  for (int p = 0; p < 4; ++p) {
    int gr = (lr >> 4) * 64 + p * 16 + (lr & 15);
    boff[p] = (size_t)(col0 + gr) * K + ch * 8;
  }

  auto stgA = [&](int q, int g, int kt) {
    async_copy16(A + aoff[g] + kt * 64, lds + q * 65536 + g * 8192 + tid * 16);
  };
  auto stgB = [&](int q, int p, int kt) {
    async_copy16(Bw + boff[p] + kt * 64, lds + q * 65536 + 32768 + p * 8192 + tid * 16);
  };

  f32x4 zero = {0.f, 0.f, 0.f, 0.f};
  f32x4 acc[8][4];
#pragma unroll
  for (int mi = 0; mi < 8; ++mi)
#pragma unroll
    for (int ni = 0; ni < 4; ++ni) acc[mi][ni] = zero;

  int nt = K >> 6;  // 32

  stgB(0, 0, 0); stgB(0, 1, 0); stgB(0, 2, 0); stgB(0, 3, 0);
  stgA(0, 0, 0); stgA(0, 1, 0); stgA(0, 2, 0); stgA(0, 3, 0);
  asm volatile("s_waitcnt vmcnt(0)" ::: "memory");
  __builtin_amdgcn_sched_barrier(0);
  __builtin_amdgcn_s_barrier();
  __builtin_amdgcn_sched_barrier(0);

#pragma unroll 1
  for (int t = 0; t < nt; ++t) {
    int q = t & 1, qn = q ^ 1;
    int kt = (t + 1 < nt) ? (t + 1) : t;
    const char* Ab = lds + q * 65536;
    const char* Bb = Ab + 32768;
    bf16x8 bf[4][2];

#define QKV_PHASE(MI0, STG0, STG1, WAIT)                                        \
    {                                                                           \
      int r0 = ((MI0) >> 1) * 64 + wm * 32 + mr;                                \
      int r1 = r0 + 16;                                                         \
      bf16x8 a00 = *(const bf16x8*)(Ab + r0 * 128 + ((kg * 16) ^ ((r0 & 7) << 4)));      \
      bf16x8 a01 = *(const bf16x8*)(Ab + r0 * 128 + ((64 + kg * 16) ^ ((r0 & 7) << 4))); \
      bf16x8 a10 = *(const bf16x8*)(Ab + r1 * 128 + ((kg * 16) ^ ((r1 & 7) << 4)));      \
      bf16x8 a11 = *(const bf16x8*)(Ab + r1 * 128 + ((64 + kg * 16) ^ ((r1 & 7) << 4))); \
      STG0; STG1;                                                               \
      __builtin_amdgcn_sched_barrier(0);                                        \
      asm volatile("s_waitcnt vmcnt(" #WAIT ")" ::: "memory");                  \
      __builtin_amdgcn_s_barrier();                                             \
      asm volatile("s_waitcnt lgkmcnt(0)" ::: "memory");                        \
      __builtin_amdgcn_sched_barrier(0);                                        \
      __builtin_amdgcn_s_setprio(1);                                            \
      _Pragma("unroll")                                                         \
      for (int ni = 0; ni < 4; ++ni) {                                          \
        acc[MI0][ni] = MFMA16(a00, bf[ni][0], acc[MI0][ni]);                    \
        acc[MI0][ni] = MFMA16(a01, bf[ni][1], acc[MI0][ni]);                    \
        acc[(MI0) + 1][ni] = MFMA16(a10, bf[ni][0], acc[(MI0) + 1][ni]);        \
        acc[(MI0) + 1][ni] = MFMA16(a11, bf[ni][1], acc[(MI0) + 1][ni]);        \
      }                                                                         \
      __builtin_amdgcn_s_setprio(0);                                            \
      __builtin_amdgcn_sched_barrier(0);                                        \
      __builtin_amdgcn_s_barrier();                                             \
      __builtin_amdgcn_sched_barrier(0);                                        \
    }

#pragma unroll
    for (int ni = 0; ni < 4; ++ni) {
      int rb = ni * 64 + wn * 16 + mr;
      bf[ni][0] = *(const bf16x8*)(Bb + rb * 128 + ((kg * 16) ^ ((rb & 7) << 4)));
      bf[ni][1] = *(const bf16x8*)(Bb + rb * 128 + ((64 + kg * 16) ^ ((rb & 7) << 4)));
    }
    QKV_PHASE(0, stgB(qn, 0, kt), stgB(qn, 1, kt), 4)
    QKV_PHASE(2, stgB(qn, 2, kt), stgB(qn, 3, kt), 5)
    QKV_PHASE(4, stgA(qn, 0, kt), stgA(qn, 1, kt), 6)
    QKV_PHASE(6, stgA(qn, 2, kt), stgA(qn, 3, kt), 3)
#undef QKV_PHASE
  }
  asm volatile("s_waitcnt vmcnt(0)" ::: "memory");
  __syncthreads();

  // ---- fused RoPE epilogue (q pre-scaled by cscale) ----
  char* tb = &lds[0];
  int s = col0 >> 11;
  int h0 = (col0 >> 7) & 15;
  int b = row0 >> 11, t0 = row0 & 2047;
#pragma unroll
  for (int mi = 0; mi < 8; ++mi)
#pragma unroll
    for (int ni = 0; ni < 4; ++ni)
#pragma unroll
      for (int jj = 0; jj < 4; ++jj) {
        int rl = wm * 128 + mi * 16 + kg * 4 + jj;
        int cb = (wn * 64 + ni * 16 + mr) * 2;
        *(bf16_t*)(tb + rl * 512 + (cb ^ ((rl & 7) << 4))) = (bf16_t)acc[mi][ni][jj];
      }
  __syncthreads();
  int r = tid >> 1, hs = tid & 1;
  const char* rowb = tb + r * 512;
  int sz = (r & 7) << 4;
  int t = t0 + r;
  bf16_t* dst = (s == 0 ? qo : ko) + ((size_t)((b * 16 + h0 + hs) * 2048 + t)) * 128;
  float tf = (float)t;
  const float cinv = -0.20762050593046014f;  // -log2(10000)/64
  float postm = (s == 0) ? 0.12751744f : 1.0f;  // (1/sqrt(128))*log2(e) folded into q
  bf16x8 vin[16];
#pragma unroll
  for (int m = 0; m < 16; ++m)
    vin[m] = *(const bf16x8*)(rowb + ((hs * 256 + m * 16) ^ sz));
#pragma unroll
  for (int m = 0; m < 8; ++m) {
    bf16x8 o1, o2;
#pragma unroll
    for (int e = 0; e < 8; ++e) {
      float ang = tf * exp2f((float)(m * 8 + e) * cinv);
      float sv = __sinf(ang), cv = __cosf(ang);
      float x1 = (float)vin[m][e], x2 = (float)vin[m + 8][e];
      o1[e] = (bf16_t)((x1 * cv - x2 * sv) * postm);
      o2[e] = (bf16_t)((x2 * cv + x1 * sv) * postm);
    }
    *(bf16x8*)(dst + m * 8) = o1;
    *(bf16x8*)(dst + 64 + m * 8) = o2;
  }
}

// ------- GEMM 256x128 tile, BK=64, 512 thr, depth-2 (R6 proven body) -------
template <int MODE>
__global__ __launch_bounds__(512, 2) void gemm256(
    const bf16_t* __restrict__ A, const bf16_t* __restrict__ Bw, float* __restrict__ C,
    bf16_t* __restrict__ vto, int M, int N, int K, int nby, int colbase) {
  __shared__ __align__(16) char lds[147456];
  int tid = threadIdx.x;
  int w = tid >> 6, lane = tid & 63;
  int wm = w >> 1, wn = w & 1;
  int mr = lane & 15, kg = lane >> 4;

  int nwg = gridDim.x;
  int orig = blockIdx.x;
  int wgid = (orig & 7) * (nwg >> 3) + (orig >> 3);
  int by = wgid % nby, bx = wgid / nby;
  int row0 = by * 256, col0 = colbase + bx * 128;

  size_t aoff[4], boff[2];
#pragma unroll
  for (int it = 0; it < 4; ++it) {
    int c = tid + it * 512;
    int r = c >> 3;
    int chs = (c & 7) ^ (r & 7);
    aoff[it] = (size_t)(row0 + r) * K + chs * 8;
  }
#pragma unroll
  for (int it = 0; it < 2; ++it) {
    int c = tid + it * 512;
    int r = c >> 3;
    int chs = (c & 7) ^ (r & 7);
    boff[it] = (size_t)(col0 - colbase + r) * K + chs * 8;
  }

  auto stageA = [&](int buf, int kt, int half) {
    char* Ad = &lds[buf * 49152];
#pragma unroll
    for (int it = half * 2; it < half * 2 + 2; ++it)
      async_copy16(A + aoff[it] + kt * 64, Ad + (tid + it * 512) * 16);
  };
  auto stageB = [&](int buf, int kt) {
    char* Bd = &lds[buf * 49152 + 32768];
#pragma unroll
    for (int it = 0; it < 2; ++it)
      async_copy16(Bw + boff[it] + kt * 64, Bd + (tid + it * 512) * 16);
  };

  f32x4 zero = {0.f, 0.f, 0.f, 0.f};
  f32x4 acc[4][4];
#pragma unroll
  for (int mi = 0; mi < 4; ++mi)
#pragma unroll
    for (int ni = 0; ni < 4; ++ni) acc[mi][ni] = zero;

  int nt = K >> 6;
  stageA(0, 0, 0); stageA(0, 0, 1); stageB(0, 0);
  stageA(1, 1, 0); stageA(1, 1, 1); stageB(1, 1);
  asm volatile("s_waitcnt vmcnt(6)" ::: "memory");
  __builtin_amdgcn_sched_barrier(0);
  __builtin_amdgcn_s_barrier();
  __builtin_amdgcn_sched_barrier(0);

#pragma unroll 1
  for (int t = 0; t < nt; ++t) {
    int cur = t % 3;
    int nxt = (t + 2) % 3;
    int kt2 = (t + 2 < nt) ? (t + 2) : t;
    const char* Ab = &lds[cur * 49152];
    const char* Bb = &lds[cur * 49152 + 32768];
    bf16x8 af[4][2], bfr[4][2];
#pragma unroll
    for (int mi = 0; mi < 4; ++mi) {
      int row = wm * 64 + mi * 16 + mr;
      const char* rb = Ab + row * 128;
      int sz = (row & 7) << 4;
      af[mi][0] = *(const bf16x8*)(rb + ((kg * 16) ^ sz));
      af[mi][1] = *(const bf16x8*)(rb + ((64 + kg * 16) ^ sz));
    }
#pragma unroll
    for (int ni = 0; ni < 4; ++ni) {
      int row = wn * 64 + ni * 16 + mr;
      const char* rb = Bb + row * 128;
      int sz = (row & 7) << 4;
      bfr[ni][0] = *(const bf16x8*)(rb + ((kg * 16) ^ sz));
      bfr[ni][1] = *(const bf16x8*)(rb + ((64 + kg * 16) ^ sz));
    }
    stageA(nxt, kt2, 0);
    __builtin_amdgcn_s_setprio(1);
#pragma unroll
    for (int mi = 0; mi < 4; ++mi) {
      acc[mi][0] = MFMA16(af[mi][0], bfr[0][0], acc[mi][0]);
      acc[mi][0] = MFMA16(af[mi][1], bfr[0][1], acc[mi][0]);
    }
    __builtin_amdgcn_s_setprio(0);
    stageA(nxt, kt2, 1);
    __builtin_amdgcn_s_setprio(1);
#pragma unroll
    for (int mi = 0; mi < 4; ++mi) {
      acc[mi][1] = MFMA16(af[mi][0], bfr[1][0], acc[mi][1]);
      acc[mi][1] = MFMA16(af[mi][1], bfr[1][1], acc[mi][1]);
    }
    __builtin_amdgcn_s_setprio(0);
    stageB(nxt, kt2);
    __builtin_amdgcn_s_setprio(1);
#pragma unroll
    for (int mi = 0; mi < 4; ++mi) {
      acc[mi][2] = MFMA16(af[mi][0], bfr[2][0], acc[mi][2]);
      acc[mi][2] = MFMA16(af[mi][1], bfr[2][1], acc[mi][2]);
      acc[mi][3] = MFMA16(af[mi][0], bfr[3][0], acc[mi][3]);
      acc[mi][3] = MFMA16(af[mi][1], bfr[3][1], acc[mi][3]);
    }
    __builtin_amdgcn_s_setprio(0);
    asm volatile("s_waitcnt vmcnt(6)" ::: "memory");
    __builtin_amdgcn_sched_barrier(0);
    __builtin_amdgcn_s_barrier();
    __builtin_amdgcn_sched_barrier(0);
  }
  asm volatile("s_waitcnt vmcnt(0)" ::: "memory");
  __syncthreads();

  if (MODE == 0) {
#pragma unroll
    for (int mi = 0; mi < 4; ++mi)
#pragma unroll
      for (int ni = 0; ni < 4; ++ni)
#pragma unroll
        for (int jj = 0; jj < 4; ++jj) {
          int row = row0 + wm * 64 + mi * 16 + kg * 4 + jj;
          int col = col0 + wn * 64 + ni * 16 + mr;
          C[(size_t)row * N + col] = acc[mi][ni][jj];
        }
  } else {
    char* tb = &lds[0];
    int h = (col0 >> 7) & 15;
    int b = row0 >> 11, t0 = row0 & 2047;
#pragma unroll
    for (int mi = 0; mi < 4; ++mi)
#pragma unroll
      for (int ni = 0; ni < 4; ++ni)
#pragma unroll
        for (int jj = 0; jj < 4; ++jj) {
          int rloc = wm * 64 + mi * 16 + kg * 4 + jj;
          int cloc = wn * 64 + ni * 16 + mr;
          *(bf16_t*)(tb + cloc * 512 + ((rloc * 2) ^ ((cloc & 7) << 4))) =
              (bf16_t)acc[mi][ni][jj];
        }
    __syncthreads();
    int d = tid >> 2, qt = tid & 3;
    const char* rowb = tb + d * 512;
    int sz = (d & 7) << 4;
    bf16_t* dst = vto + ((size_t)((b * 16 + h) * 128 + d)) * 2048 + t0 + qt * 64;
#pragma unroll
    for (int m2 = 0; m2 < 8; ++m2)
      *(bf16x8*)(dst + m2 * 8) = *(const bf16x8*)(rowb + ((qt * 128 + m2 * 16) ^ sz));
  }
}

// ---------------- causal flash attention (v4: single-buffer, 4 blocks/CU) ----------------
// LDS 40KB (Ks 16 + Vs 16 + plds 8) -> 4 blocks/CU; TLP replaces the double-buffer.
// q pre-scaled in gemm_qkv, so no per-tile scale mul.
__global__ __launch_bounds__(256, 4) void attn_kernel(
    const bf16_t* __restrict__ qg, const bf16_t* __restrict__ kgl,
    const bf16_t* __restrict__ vtg, bf16_t* __restrict__ og) {
  __shared__ __align__(16) bf16_t Ks[64 * 128];
  __shared__ __align__(16) bf16_t Vs[128 * 64];
  __shared__ __align__(16) bf16_t plds[4][1024];
  const int T = 2048;
  int tid = threadIdx.x;
  int w = tid >> 6, lane = tid & 63;
  int mr = lane & 15, kg = lane >> 4;
  int swz = (mr & 7) << 4;

  int L = blockIdx.y * 16 + blockIdx.x;
  int role = (L & 7) * 64 + (L >> 3);
  int bx = role & 15, bh = role >> 4;

  const bf16_t* Q = qg + (size_t)bh * T * 128;
  const bf16_t* K = kgl + (size_t)bh * T * 128;
  const bf16_t* Vt = vtg + (size_t)bh * 128 * T;

  int sb = tid * 16;
  int krl = sb >> 8;
  int kc = (sb & 255) ^ ((krl & 7) << 4);
  size_t ksrc = (size_t)krl * 128 + (kc >> 1);
  int vdl = sb >> 7;
  int vc = (sb & 127) ^ ((vdl & 7) << 4);
  size_t vsrc = (size_t)vdl * 2048 + (vc >> 1);

  auto stage = [&](int kb) {
#pragma unroll
    for (int it = 0; it < 4; ++it)
      async_copy16(K + (size_t)(kb + it * 16) * 128 + ksrc, &Ks[it * 2048 + tid * 8]);
#pragma unroll
    for (int it = 0; it < 4; ++it)
      async_copy16(Vt + (size_t)it * 65536 + kb + vsrc, &Vs[it * 2048 + tid * 8]);
  };

  f32x4 zero = {0.f, 0.f, 0.f, 0.f};
  bf16_t* P = &plds[w][0];
  int b = bh >> 4, h = bh & 15;

#pragma unroll 1
  for (int ph = 0; ph < 2; ++ph) {
    int qb = ph ? bx : (31 - bx);
    int qr0 = qb * 64 + w * 16;
    bf16x8 qf[4];
#pragma unroll
    for (int db = 0; db < 4; ++db)
      qf[db] = *(const bf16x8*)(Q + (size_t)(qr0 + mr) * 128 + db * 32 + kg * 8);

    f32x4 acc[8];
#pragma unroll
    for (int d2 = 0; d2 < 8; ++d2) acc[d2] = zero;
    float mrun[4] = {-1e30f, -1e30f, -1e30f, -1e30f};
    float lpart[4] = {0.f, 0.f, 0.f, 0.f};

    int nj = qb + 1;
#pragma unroll 1
    for (int j = 0; j < nj; ++j) {
      __syncthreads();               // close previous tile's reads
      stage(j * 64);
      asm volatile("s_waitcnt vmcnt(0)" ::: "memory");
      __builtin_amdgcn_sched_barrier(0);
      __syncthreads();               // all waves' loads landed
      const char* KsB = (const char*)&Ks[0];
      const char* VsB = (const char*)&Vs[0];
      int kb = j * 64;
      f32x4 s[4];
      __builtin_amdgcn_s_setprio(1);
#pragma unroll
      for (int ntl = 0; ntl < 4; ++ntl) {
        s[ntl] = zero;
        int rowb = (ntl * 16 + mr) * 256;
#pragma unroll
        for (int db = 0; db < 4; ++db) {
          bf16x8 kf = *(const bf16x8*)(KsB + rowb + ((db * 64 + kg * 16) ^ swz));
          s[ntl] = MFMA16(qf[db], kf, s[ntl]);
        }
      }
      __builtin_amdgcn_s_setprio(0);
      // ---- mask + per-lane max (scale pre-folded into q) ----
      float pvv[4][4];
      float lmax[4] = {-3e38f, -3e38f, -3e38f, -3e38f};
      bool diag = (j == qb);
#pragma unroll
      for (int ntl = 0; ntl < 4; ++ntl)
#pragma unroll
        for (int jj = 0; jj < 4; ++jj) {
          float v = s[ntl][jj];
          if (diag && (kb + ntl * 16 + mr) > (qr0 + kg * 4 + jj)) v = -1e30f;
          pvv[ntl][jj] = v;
          lmax[jj] = fmaxf(lmax[jj], v);
        }
      bool ok = true;
#pragma unroll
      for (int jj = 0; jj < 4; ++jj) ok &= (lmax[jj] <= mrun[jj] + 8.0f);
      if (!__all(ok)) {
        float tmax[4];
#pragma unroll
        for (int jj = 0; jj < 4; ++jj) tmax[jj] = lmax[jj];
#pragma unroll
        for (int m = 1; m < 16; m <<= 1)
#pragma unroll
          for (int jj = 0; jj < 4; ++jj)
            tmax[jj] = fmaxf(tmax[jj], __shfl_xor(tmax[jj], m, 64));
#pragma unroll
        for (int jj = 0; jj < 4; ++jj) {
          float mn = fmaxf(mrun[jj], tmax[jj]);
          float corr = __builtin_amdgcn_exp2f(mrun[jj] - mn);
          mrun[jj] = mn;
          lpart[jj] *= corr;
#pragma unroll
          for (int d2 = 0; d2 < 8; ++d2) acc[d2][jj] *= corr;
        }
      }
#pragma unroll
      for (int ntl = 0; ntl < 4; ++ntl)
#pragma unroll
        for (int jj = 0; jj < 4; ++jj) {
          float p = __builtin_amdgcn_exp2f(pvv[ntl][jj] - mrun[jj]);
          pvv[ntl][jj] = p;
          lpart[jj] += p;
        }
#pragma unroll
      for (int ntl = 0; ntl < 4; ++ntl)
#pragma unroll
        for (int jj = 0; jj < 4; ++jj) {
          int rr = kg * 4 + jj;
          int cbyte = (mr + ntl * 16) * 2;
          *(bf16_t*)((char*)P + rr * 128 + (cbyte ^ ((rr & 7) << 4))) = (bf16_t)pvv[ntl][jj];
        }
      __builtin_amdgcn_s_setprio(1);
#pragma unroll
      for (int ks = 0; ks < 2; ++ks) {
        int cb = (ks * 32 + kg * 8) * 2;
        bf16x8 pa = *(const bf16x8*)((const char*)P + mr * 128 + (cb ^ ((mr & 7) << 4)));
#pragma unroll
        for (int d2 = 0; d2 < 8; ++d2) {
          bf16x8 vf = *(const bf16x8*)(VsB + (d2 * 16 + mr) * 128 + ((ks * 64 + kg * 16) ^ swz));
          acc[d2] = MFMA16(pa, vf, acc[d2]);
        }
      }
      __builtin_amdgcn_s_setprio(0);
    }
    // ---- epilogue: one l-reduction per phase ----
#pragma unroll
    for (int m = 1; m < 16; m <<= 1)
#pragma unroll
      for (int jj = 0; jj < 4; ++jj) lpart[jj] += __shfl_xor(lpart[jj], m, 64);
#pragma unroll
    for (int jj = 0; jj < 4; ++jj) {
      float invl = 1.0f / lpart[jj];
      int t = qr0 + kg * 4 + jj;
      size_t row = (size_t)b * 2048 + h * 128 + (t >> 4);
      bf16_t* orow = og + row * 2048 + (t & 15) * 128;
#pragma unroll
      for (int d2 = 0; d2 < 8; ++d2)
        orow[d2 * 16 + mr] = (bf16_t)(acc[d2][jj] * invl);
    }
  }
}

extern "C" void kernel_launch(void* const* d_in, const int* in_sizes, int n_in,
                              void* d_out, int out_size, void* d_ws, size_t ws_size,
                              hipStream_t stream) {
  const float* x = (const float*)d_in[0];      // [2,2048,2048]
  const float* wqkv = (const float*)d_in[1];   // [6144,2048]
  const float* wproj = (const float*)d_in[2];  // [2048,2048]
  float* out = (float*)d_out;                  // [2,2048,2048]
  char* ws = (char*)d_ws;

  const size_t OFF_WQKV = 16777216;
  const size_t OFF_Q = 41943040;
  const size_t OFF_K = 58720256;
  const size_t OFF_VT = 75497472;

  bf16_t* xb = (bf16_t*)(ws);
  bf16_t* wqkvb = (bf16_t*)(ws + OFF_WQKV);
  bf16_t* g_q = (bf16_t*)(ws + OFF_Q);
  bf16_t* g_k = (bf16_t*)(ws + OFF_K);
  bf16_t* g_vt = (bf16_t*)(ws + OFF_VT);
  bf16_t* g_att = (bf16_t*)(ws);               // alias xb (dead after gemm1)
  bf16_t* wprojb = (bf16_t*)(ws + OFF_WQKV);   // alias wqkvb (dead after gemm1)

  cast_f32_bf16<<<2048, 256, 0, stream>>>(x, xb, 8388608 / 8);
  cast_f32_bf16<<<2048, 256, 0, stream>>>(wqkv, wqkvb, 12582912 / 8);
  // d1: q,k columns (N=4096) as 256^2 tiles -> 256 blocks = 1 full CU round
  gemm_qkv<<<256, 512, 0, stream>>>(xb, wqkvb, g_q, g_k, 2048);
  // d2: v columns (N=2048) as 256x128 tiles -> 256 blocks = 1 full CU round
  gemm256<1><<<256, 512, 0, stream>>>(xb, wqkvb + (size_t)4096 * 2048, nullptr, g_vt,
                                      4096, 2048, 2048, 16, 4096);
  cast_f32_bf16<<<2048, 256, 0, stream>>>(wproj, wprojb, 4194304 / 8);
  attn_kernel<<<dim3(16, 32), 256, 0, stream>>>(g_q, g_k, g_vt, g_att);
  // output projection (256x128 tiles, 256 blocks = 1 full CU round)
  gemm256<0><<<256, 512, 0, stream>>>(g_att, wprojb, out, nullptr, 4096, 2048, 2048, 16, 0);
}